// Round 11
// baseline (331.003 us; speedup 1.0000x reference)
//
#include <hip/hip_runtime.h>

// ---------------------------------------------------------------------------
// SelfAttention: x -> QKV proj -> RMSNorm -> RoPE -> softmax attn -> out proj
// B=2 S=2048 DIM=2048 NH=16 HD=128  (all shapes hard-coded)
// ---------------------------------------------------------------------------

typedef __attribute__((ext_vector_type(8))) short bf16x8;
typedef __attribute__((ext_vector_type(4))) float f32x4;

__device__ __forceinline__ unsigned short f2bf(float f) {
  unsigned int u = __builtin_bit_cast(unsigned int, f);
  u = (u + 0x7FFFu + ((u >> 16) & 1u)) >> 16;  // RNE
  return (unsigned short)u;
}
__device__ __forceinline__ float bf2f(unsigned short h) {
  unsigned int u = ((unsigned int)h) << 16;
  return __builtin_bit_cast(float, u);
}

#define GLOAD16(gp, lp)                                                        \
  __builtin_amdgcn_global_load_lds(                                            \
      (__attribute__((address_space(1))) void*)(gp),                           \
      (__attribute__((address_space(3))) void*)(lp), 16, 0, 0)

// ---------------- fused prep: x f32->bf16 convert + 4 weight transposes -----
__global__ __launch_bounds__(256) void k_prep(const float* __restrict__ x,
                                              unsigned short* __restrict__ xb,
                                              const float* __restrict__ qw,
                                              const float* __restrict__ kw,
                                              const float* __restrict__ vw,
                                              const float* __restrict__ ow,
                                              unsigned short* __restrict__ qkT,
                                              unsigned short* __restrict__ vT,
                                              unsigned short* __restrict__ oT) {
  const int bid = blockIdx.x;
  const int tid = threadIdx.x;
  if (bid >= 4096) {
    const int i = (bid - 4096) * 256 + tid;    // 4096*256 = 1,048,576 = n/8
    const float4* p = (const float4*)x + (size_t)i * 2;
    float4 a = p[0], b = p[1];
    bf16x8 v;
    v[0] = (short)f2bf(a.x); v[1] = (short)f2bf(a.y);
    v[2] = (short)f2bf(a.z); v[3] = (short)f2bf(a.w);
    v[4] = (short)f2bf(b.x); v[5] = (short)f2bf(b.y);
    v[6] = (short)f2bf(b.z); v[7] = (short)f2bf(b.w);
    *(bf16x8*)(xb + (size_t)i * 8) = v;
    return;
  }
  __shared__ float tile[64][65];
  const int mat = bid >> 10, t10 = bid & 1023;
  const float* in = (mat == 0) ? qw : (mat == 1) ? kw : (mat == 2) ? vw : ow;
  unsigned short* out = (mat == 0) ? qkT
                      : (mat == 1) ? (qkT + (size_t)2048 * 2048)
                      : (mat == 2) ? vT : oT;
  const int r0 = (t10 >> 5) * 64, c0 = (t10 & 31) * 64;
#pragma unroll
  for (int i = 0; i < 4; i++) {
    const int fi = tid + i * 256;
    const int row = fi >> 4, c4 = fi & 15;
    float4 v = *(const float4*)(in + (size_t)(r0 + row) * 2048 + c0 + c4 * 4);
    tile[row][c4 * 4 + 0] = v.x; tile[row][c4 * 4 + 1] = v.y;
    tile[row][c4 * 4 + 2] = v.z; tile[row][c4 * 4 + 3] = v.w;
  }
  __syncthreads();
#pragma unroll
  for (int i = 0; i < 2; i++) {
    const int oi = tid + i * 256;
    const int c = oi >> 3, r8 = oi & 7;
    bf16x8 o;
#pragma unroll
    for (int j = 0; j < 8; j++) o[j] = (short)f2bf(tile[r8 * 8 + j][c]);
    *(bf16x8*)(out + (size_t)(c0 + c) * 2048 + r0 + r8 * 8) = o;
  }
}

// ---------------- shared staging helper (512-thread blocks) -----------------
__device__ __forceinline__ void stage_half(const unsigned short* __restrict__ src,
                                           int K, unsigned short* dst, int tid) {
#pragma unroll
  for (int j = 0; j < 2; j++) {
    const int li = tid + j * 512;
    const int r = li >> 3;
    const int c16 = (li & 7) ^ (r & 7);
    GLOAD16(src + (size_t)r * K + c16 * 8, (char*)dst + li * 16);
  }
}

// ---------------- 256x256 8-phase GEMM (T2+T3+T4+T5) -- Yqk only ------------
__global__ __launch_bounds__(512, 2) void k_gemm_yqk(const unsigned short* __restrict__ A,
                                                     const unsigned short* __restrict__ BT,
                                                     unsigned short* __restrict__ Cout) {
  __shared__ unsigned short As[2][256 * 64];
  __shared__ unsigned short Bs[2][256 * 64];
  const int tid = threadIdx.x;
  const int lane = tid & 63, w = tid >> 6;
  const int g = lane >> 4, cc = lane & 15;
  const int wm = (w >> 2) * 128, wn = (w & 3) * 64;
  const int swz = (cc & 7) << 4;
  const int N = 4096, K = 2048;
  int id = blockIdx.x;
  id = (id & 7) * 32 + (id >> 3);              // 256 wgs -> 32/XCD contiguous
  const int m0 = (id >> 4) * 256, n0 = (id & 15) * 256;
  f32x4 acc[8][4] = {};
  const int T = K >> 6;                        // 32 K-tiles

  stage_half(BT + (size_t)n0 * K, K, Bs[0], tid);
  stage_half(A + (size_t)m0 * K, K, As[0], tid);
  stage_half(BT + (size_t)(n0 + 128) * K, K, Bs[0] + 8192, tid);
  stage_half(A + (size_t)(m0 + 128) * K, K, As[0] + 8192, tid);
  stage_half(BT + (size_t)n0 * K + 64, K, Bs[1], tid);
  stage_half(A + (size_t)m0 * K + 64, K, As[1], tid);
  asm volatile("s_waitcnt vmcnt(4)" ::: "memory");
  __builtin_amdgcn_s_barrier();

  for (int t = 0; t < T; ++t) {
    const int c = t & 1;
    const char* Ac = (const char*)As[c];
    const char* Bc = (const char*)Bs[c];
    bf16x8 ar[4][2], br[4][2];
    // -------- phase 1
#pragma unroll
    for (int m = 0; m < 4; m++)
#pragma unroll
      for (int kk = 0; kk < 2; kk++)
        ar[m][kk] = *(const bf16x8*)(Ac + (wm + m * 16 + cc) * 128 +
                                     ((kk * 64 + g * 16) ^ swz));
#pragma unroll
    for (int n = 0; n < 2; n++)
#pragma unroll
      for (int kk = 0; kk < 2; kk++)
        br[n][kk] = *(const bf16x8*)(Bc + (wn + n * 16 + cc) * 128 +
                                     ((kk * 64 + g * 16) ^ swz));
    stage_half(BT + (size_t)(n0 + 128) * K + ((t + 1) & (T - 1)) * 64, K,
               Bs[c ^ 1] + 8192, tid);
    __builtin_amdgcn_s_barrier();
    __builtin_amdgcn_sched_barrier(0);
    __builtin_amdgcn_s_setprio(1);
#pragma unroll
    for (int kk = 0; kk < 2; kk++)
#pragma unroll
      for (int m = 0; m < 4; m++)
#pragma unroll
        for (int n = 0; n < 2; n++)
          acc[m][n] = __builtin_amdgcn_mfma_f32_16x16x32_bf16(ar[m][kk], br[n][kk],
                                                              acc[m][n], 0, 0, 0);
    __builtin_amdgcn_s_setprio(0);
    __builtin_amdgcn_s_barrier();
    __builtin_amdgcn_sched_barrier(0);
    // -------- phase 2
#pragma unroll
    for (int n = 2; n < 4; n++)
#pragma unroll
      for (int kk = 0; kk < 2; kk++)
        br[n][kk] = *(const bf16x8*)(Bc + (wn + n * 16 + cc) * 128 +
                                     ((kk * 64 + g * 16) ^ swz));
    stage_half(A + (size_t)(m0 + 128) * K + ((t + 1) & (T - 1)) * 64, K,
               As[c ^ 1] + 8192, tid);
    __builtin_amdgcn_s_barrier();
    __builtin_amdgcn_sched_barrier(0);
    __builtin_amdgcn_s_setprio(1);
#pragma unroll
    for (int kk = 0; kk < 2; kk++)
#pragma unroll
      for (int m = 0; m < 4; m++)
#pragma unroll
        for (int n = 2; n < 4; n++)
          acc[m][n] = __builtin_amdgcn_mfma_f32_16x16x32_bf16(ar[m][kk], br[n][kk],
                                                              acc[m][n], 0, 0, 0);
    __builtin_amdgcn_s_setprio(0);
    __builtin_amdgcn_s_barrier();
    __builtin_amdgcn_sched_barrier(0);
    // -------- phase 3
#pragma unroll
    for (int m = 0; m < 4; m++)
#pragma unroll
      for (int kk = 0; kk < 2; kk++)
        ar[m][kk] = *(const bf16x8*)(Ac + (wm + (m + 4) * 16 + cc) * 128 +
                                     ((kk * 64 + g * 16) ^ swz));
    stage_half(BT + (size_t)n0 * K + ((t + 2) & (T - 1)) * 64, K, Bs[c], tid);
    __builtin_amdgcn_s_barrier();
    __builtin_amdgcn_sched_barrier(0);
    __builtin_amdgcn_s_setprio(1);
#pragma unroll
    for (int kk = 0; kk < 2; kk++)
#pragma unroll
      for (int m = 0; m < 4; m++)
#pragma unroll
        for (int n = 0; n < 2; n++)
          acc[m + 4][n] = __builtin_amdgcn_mfma_f32_16x16x32_bf16(ar[m][kk], br[n][kk],
                                                                  acc[m + 4][n], 0, 0, 0);
    __builtin_amdgcn_s_setprio(0);
    __builtin_amdgcn_s_barrier();
    __builtin_amdgcn_sched_barrier(0);
    // -------- phase 4
    stage_half(A + (size_t)m0 * K + ((t + 2) & (T - 1)) * 64, K, As[c], tid);
    __builtin_amdgcn_s_setprio(1);
#pragma unroll
    for (int kk = 0; kk < 2; kk++)
#pragma unroll
      for (int m = 0; m < 4; m++)
#pragma unroll
        for (int n = 2; n < 4; n++)
          acc[m + 4][n] = __builtin_amdgcn_mfma_f32_16x16x32_bf16(ar[m][kk], br[n][kk],
                                                                  acc[m + 4][n], 0, 0, 0);
    __builtin_amdgcn_s_setprio(0);
    if (t < T - 2)
      asm volatile("s_waitcnt vmcnt(4)" ::: "memory");
    else
      asm volatile("s_waitcnt vmcnt(0)" ::: "memory");
    __builtin_amdgcn_sched_barrier(0);
    __builtin_amdgcn_s_barrier();
    __builtin_amdgcn_sched_barrier(0);
  }

#pragma unroll
  for (int mi = 0; mi < 8; mi++)
#pragma unroll
    for (int n = 0; n < 4; n++) {
      const int col = n0 + wn + n * 16 + cc;
#pragma unroll
      for (int j = 0; j < 4; j++) {
        const int row = m0 + wm + mi * 16 + g * 4 + j;
        Cout[(size_t)row * N + col] = f2bf(acc[mi][n][j]);
      }
    }
}

// ---------------- 256x128 8-phase GEMM (new R11 variant) ---------------------
// BM=256, BN=128, BK=64, 512 threads (2M x 4N waves, 128x32 per wave).
// LDS 96KB (As 2x32K + Bs 2x16K) -> 1 block/CU; grid must be exactly 256 wgs.
// Stages per tile: ph1 B(t+1)->Bs[c^1]; ph2 A1(t+1)->As[c^1]+8192;
// ph3 none; ph4 A0(t+2)->As[c] (safe: ph3's reads of that region drained by
// ph3-end barrier). vmcnt(2) once per tile (only A0(t+2) in flight).
template <int OUTF32, int BIASROW>
__global__ __launch_bounds__(512, 2) void k_gemm_n128(const unsigned short* __restrict__ A,
                                                      const unsigned short* __restrict__ BT,
                                                      void* __restrict__ Cout,
                                                      const float* __restrict__ bias,
                                                      int N, int K) {
  __shared__ unsigned short As[2][256 * 64];
  __shared__ unsigned short Bs[2][128 * 64];
  const int tid = threadIdx.x;
  const int lane = tid & 63, w = tid >> 6;
  const int g = lane >> 4, cc = lane & 15;
  const int wm = (w >> 2) * 128, wn = (w & 3) * 32;
  const int swz = (cc & 7) << 4;
  const int nbx = N >> 7;                      // N/128 tiles along n
  int id = blockIdx.x;
  id = (id & 7) * 32 + (id >> 3);              // 256 wgs -> 32/XCD contiguous
  const int m0 = (id / nbx) * 256, n0 = (id % nbx) * 128;
  f32x4 acc[8][2] = {};
  const int T = K >> 6;                        // 32 K-tiles

  // prologue mirrors steady state "end of t=-1": A0(0),B(0),A1(0) landed,
  // A0(1) in flight.
  stage_half(A + (size_t)m0 * K, K, As[0], tid);
  stage_half(BT + (size_t)n0 * K, K, Bs[0], tid);
  stage_half(A + (size_t)(m0 + 128) * K, K, As[0] + 8192, tid);
  stage_half(A + (size_t)m0 * K + 64, K, As[1], tid);
  asm volatile("s_waitcnt vmcnt(2)" ::: "memory");
  __builtin_amdgcn_s_barrier();

  for (int t = 0; t < T; ++t) {
    const int c = t & 1;
    const char* Ac = (const char*)As[c];
    const char* Bc = (const char*)Bs[c];
    bf16x8 ar[4][2], br[2][2];
    // -------- phase 1: frags a(m0-3), b(0); stage B(t+1)
#pragma unroll
    for (int m = 0; m < 4; m++)
#pragma unroll
      for (int kk = 0; kk < 2; kk++)
        ar[m][kk] = *(const bf16x8*)(Ac + (wm + m * 16 + cc) * 128 +
                                     ((kk * 64 + g * 16) ^ swz));
#pragma unroll
    for (int kk = 0; kk < 2; kk++)
      br[0][kk] = *(const bf16x8*)(Bc + (wn + cc) * 128 +
                                   ((kk * 64 + g * 16) ^ swz));
    stage_half(BT + (size_t)n0 * K + ((t + 1) & (T - 1)) * 64, K, Bs[c ^ 1], tid);
    __builtin_amdgcn_s_barrier();
    __builtin_amdgcn_sched_barrier(0);
    __builtin_amdgcn_s_setprio(1);
#pragma unroll
    for (int kk = 0; kk < 2; kk++)
#pragma unroll
      for (int m = 0; m < 4; m++)
        acc[m][0] = __builtin_amdgcn_mfma_f32_16x16x32_bf16(ar[m][kk], br[0][kk],
                                                            acc[m][0], 0, 0, 0);
    __builtin_amdgcn_s_setprio(0);
    __builtin_amdgcn_s_barrier();
    __builtin_amdgcn_sched_barrier(0);
    // -------- phase 2: frag b(1); stage A1(t+1)
#pragma unroll
    for (int kk = 0; kk < 2; kk++)
      br[1][kk] = *(const bf16x8*)(Bc + (wn + 16 + cc) * 128 +
                                   ((kk * 64 + g * 16) ^ swz));
    stage_half(A + (size_t)(m0 + 128) * K + ((t + 1) & (T - 1)) * 64, K,
               As[c ^ 1] + 8192, tid);
    __builtin_amdgcn_s_barrier();
    __builtin_amdgcn_sched_barrier(0);
    __builtin_amdgcn_s_setprio(1);
#pragma unroll
    for (int kk = 0; kk < 2; kk++)
#pragma unroll
      for (int m = 0; m < 4; m++)
        acc[m][1] = __builtin_amdgcn_mfma_f32_16x16x32_bf16(ar[m][kk], br[1][kk],
                                                            acc[m][1], 0, 0, 0);
    __builtin_amdgcn_s_setprio(0);
    __builtin_amdgcn_s_barrier();
    __builtin_amdgcn_sched_barrier(0);
    // -------- phase 3: frags a(m4-7); no stage
#pragma unroll
    for (int m = 0; m < 4; m++)
#pragma unroll
      for (int kk = 0; kk < 2; kk++)
        ar[m][kk] = *(const bf16x8*)(Ac + (wm + (m + 4) * 16 + cc) * 128 +
                                     ((kk * 64 + g * 16) ^ swz));
    __builtin_amdgcn_s_barrier();
    __builtin_amdgcn_sched_barrier(0);
    __builtin_amdgcn_s_setprio(1);
#pragma unroll
    for (int kk = 0; kk < 2; kk++)
#pragma unroll
      for (int m = 0; m < 4; m++)
        acc[m + 4][0] = __builtin_amdgcn_mfma_f32_16x16x32_bf16(ar[m][kk], br[0][kk],
                                                                acc[m + 4][0], 0, 0, 0);
    __builtin_amdgcn_s_setprio(0);
    __builtin_amdgcn_s_barrier();
    __builtin_amdgcn_sched_barrier(0);
    // -------- phase 4: stage A0(t+2); MFMA; vmcnt(2); barrier
    stage_half(A + (size_t)m0 * K + ((t + 2) & (T - 1)) * 64, K, As[c], tid);
    __builtin_amdgcn_s_setprio(1);
#pragma unroll
    for (int kk = 0; kk < 2; kk++)
#pragma unroll
      for (int m = 0; m < 4; m++)
        acc[m + 4][1] = __builtin_amdgcn_mfma_f32_16x16x32_bf16(ar[m][kk], br[1][kk],
                                                                acc[m + 4][1], 0, 0, 0);
    __builtin_amdgcn_s_setprio(0);
    if (t < T - 2)
      asm volatile("s_waitcnt vmcnt(2)" ::: "memory");
    else
      asm volatile("s_waitcnt vmcnt(0)" ::: "memory");
    __builtin_amdgcn_sched_barrier(0);
    __builtin_amdgcn_s_barrier();
    __builtin_amdgcn_sched_barrier(0);
  }

#pragma unroll
  for (int mi = 0; mi < 8; mi++)
#pragma unroll
    for (int n = 0; n < 2; n++) {
      const int col = n0 + wn + n * 16 + cc;
#pragma unroll
      for (int j = 0; j < 4; j++) {
        const int row = m0 + wm + mi * 16 + g * 4 + j;
        float v = acc[mi][n][j];
        if (bias) v += BIASROW ? bias[row] : bias[col];
        if (OUTF32)
          ((float*)Cout)[(size_t)row * N + col] = v;
        else
          ((unsigned short*)Cout)[(size_t)row * N + col] = f2bf(v);
      }
    }
}

// ---------------- QK epilogue: bias + RMSNorm + RoPE -> Q,K [b,h,s,d] ------
__global__ __launch_bounds__(256) void k_qk_epi(const unsigned short* __restrict__ Yqk, // [4096][4096]
                                                const float* __restrict__ q_b,
                                                const float* __restrict__ k_b,
                                                const float* __restrict__ nqw,
                                                const float* __restrict__ nkw,
                                                const float* __restrict__ freqs, // [1024][64][2]
                                                const int* __restrict__ inner_t, // [2][2]
                                                unsigned short* __restrict__ Q,
                                                unsigned short* __restrict__ K) {
  const int row = blockIdx.x;          // b*2048 + s
  const int b = row >> 11, s = row & 2047;
  const int t = threadIdx.x;
  const unsigned short* yr = Yqk + (size_t)row * 4096;
  bf16x8 yq = *(const bf16x8*)(yr + t * 8);
  bf16x8 yk = *(const bf16x8*)(yr + 2048 + t * 8);
  float4 qb0 = *(const float4*)(q_b + t * 8), qb1 = *(const float4*)(q_b + t * 8 + 4);
  float4 kb0 = *(const float4*)(k_b + t * 8), kb1 = *(const float4*)(k_b + t * 8 + 4);
  float q[8], k[8];
  q[0] = bf2f((unsigned short)yq[0]) + qb0.x; q[1] = bf2f((unsigned short)yq[1]) + qb0.y;
  q[2] = bf2f((unsigned short)yq[2]) + qb0.z; q[3] = bf2f((unsigned short)yq[3]) + qb0.w;
  q[4] = bf2f((unsigned short)yq[4]) + qb1.x; q[5] = bf2f((unsigned short)yq[5]) + qb1.y;
  q[6] = bf2f((unsigned short)yq[6]) + qb1.z; q[7] = bf2f((unsigned short)yq[7]) + qb1.w;
  k[0] = bf2f((unsigned short)yk[0]) + kb0.x; k[1] = bf2f((unsigned short)yk[1]) + kb0.y;
  k[2] = bf2f((unsigned short)yk[2]) + kb0.z; k[3] = bf2f((unsigned short)yk[3]) + kb0.w;
  k[4] = bf2f((unsigned short)yk[4]) + kb1.x; k[5] = bf2f((unsigned short)yk[5]) + kb1.y;
  k[6] = bf2f((unsigned short)yk[6]) + kb1.z; k[7] = bf2f((unsigned short)yk[7]) + kb1.w;
  float ssq = 0.f, ssk = 0.f;
#pragma unroll
  for (int j = 0; j < 8; j++) { ssq += q[j] * q[j]; ssk += k[j] * k[j]; }
#pragma unroll
  for (int off = 32; off; off >>= 1) {
    ssq += __shfl_xor(ssq, off);
    ssk += __shfl_xor(ssk, off);
  }
  __shared__ float red[8];
  const int w = t >> 6;
  if ((t & 63) == 0) { red[w] = ssq; red[4 + w] = ssk; }
  __syncthreads();
  const float sq = red[0] + red[1] + red[2] + red[3];
  const float sk = red[4] + red[5] + red[6] + red[7];
  const float rq = __builtin_amdgcn_rsqf(sq * (1.0f / 2048.0f) + 1e-6f);
  const float rk = __builtin_amdgcn_rsqf(sk * (1.0f / 2048.0f) + 1e-6f);
  float4 nq0 = *(const float4*)(nqw + t * 8), nq1 = *(const float4*)(nqw + t * 8 + 4);
  float4 nk0 = *(const float4*)(nkw + t * 8), nk1 = *(const float4*)(nkw + t * 8 + 4);
  q[0] *= rq * nq0.x; q[1] *= rq * nq0.y; q[2] *= rq * nq0.z; q[3] *= rq * nq0.w;
  q[4] *= rq * nq1.x; q[5] *= rq * nq1.y; q[6] *= rq * nq1.z; q[7] *= rq * nq1.w;
  k[0] *= rk * nk0.x; k[1] *= rk * nk0.y; k[2] *= rk * nk0.z; k[3] *= rk * nk0.w;
  k[4] *= rk * nk1.x; k[5] *= rk * nk1.y; k[6] *= rk * nk1.z; k[7] *= rk * nk1.w;
  // RoPE: s -> (f,h,w) with HW grid 8x16x16, pairs are adjacent elems
  const int f = s >> 8, hh = (s >> 4) & 15, ww = s & 15;
  const int it0 = inner_t[b * 2], it1 = inner_t[b * 2 + 1];
  const int trow = ((f >= it0) + (f >= it0 + it1)) * 4 + f;  // SHIFT=4
#pragma unroll
  for (int jj = 0; jj < 4; jj++) {
    const int c = (t * 4 + jj) & 63;              // pair idx within head (C=64)
    const int fr = (c < 22) ? trow : ((c < 43) ? hh : ww);  // CT=22, CT+CH=43
    const float cr = freqs[((size_t)fr * 64 + c) * 2];
    const float ci = freqs[((size_t)fr * 64 + c) * 2 + 1];
    float a = q[2 * jj], bb = q[2 * jj + 1];
    q[2 * jj] = a * cr - bb * ci; q[2 * jj + 1] = a * ci + bb * cr;
    a = k[2 * jj]; bb = k[2 * jj + 1];
    k[2 * jj] = a * cr - bb * ci; k[2 * jj + 1] = a * ci + bb * cr;
  }
  // fold attn scale and log2(e) into Q (softmax done in exp2 domain)
  const float QSCALE = 0.08838834764831845f * 1.4426950408889634f;
  bf16x8 oq, ok;
#pragma unroll
  for (int j = 0; j < 8; j++) {
    oq[j] = (short)f2bf(q[j] * QSCALE);
    ok[j] = (short)f2bf(k[j]);
  }
  const int head = t >> 4, d0 = (t & 15) * 8;
  const size_t off = ((size_t)(b * 16 + head) * 2048 + s) * 128 + d0;
  *(bf16x8*)(Q + off) = oq;
  *(bf16x8*)(K + off) = ok;
}

// ---------------- flash attention (R6 version, known-good) ------------------
__global__ __launch_bounds__(512, 4) void k_attn(const unsigned short* __restrict__ Q,
                                                 const unsigned short* __restrict__ K,
                                                 const unsigned short* __restrict__ V,
                                                 unsigned short* __restrict__ O) {
  __shared__ unsigned short Ks[2][64 * 128];   // [key][d], byte ^= (key&7)<<4
  __shared__ unsigned short Vs[2][128 * 64];   // [d][key], byte ^= (d&7)<<4
  __shared__ unsigned short Ps[8 * 16 * 64];   // per-wave P [q][key], byte ^= (q&7)<<4
  const int tid = threadIdx.x;
  const int lane = tid & 63, w = tid >> 6;
  const int g = lane >> 4, cc = lane & 15;
  const int orig = blockIdx.x;                 // 512 blocks flat
  const int lid = (orig & 7) * 64 + (orig >> 3);  // XCD gets 64 consecutive lids
  const int bh = lid >> 4;                     // 4 full heads per XCD
  const int q0 = (lid & 15) * 128;
  const int b = bh >> 4, h = bh & 15;

  const unsigned short* Qb = Q + ((size_t)bh * 2048 + q0 + w * 16 + cc) * 128;
  bf16x8 qf[4];
#pragma unroll
  for (int kk = 0; kk < 4; kk++) qf[kk] = *(const bf16x8*)(Qb + kk * 32 + g * 8);

  const char* kbase = (const char*)(K + (size_t)bh * 2048 * 128);
  const char* vbase = (const char*)V + ((size_t)h * 128 * 4096 + (size_t)b * 2048) * 2;

  f32x4 acc[8] = {};
  float mloc = -3.0e38f, lloc = 0.f;           // per-lane stats for q = w*16+cc
  char* Pb = (char*)Ps + w * 2048 + cc * 128;
  const int psw = (cc & 7) << 4;
  const int gbase = (lane & 48) | (((lane >> 4) & 3) << 2);  // lane g*16 + g*4
  const f32x4 vzero = {0.f, 0.f, 0.f, 0.f};

#define ATTN_STAGE(s0, bi)                                                     \
  {                                                                            \
    const char* kt0 = kbase + (size_t)(s0) * 256;                              \
    const char* vt0 = vbase + (size_t)(s0) * 2;                                \
    char* Kd = (char*)(Ks[bi]);                                                \
    char* Vd = (char*)(Vs[bi]);                                                \
    _Pragma("unroll") for (int i = 0; i < 2; i++) {                            \
      const int li = i * 512 + tid;                                            \
      const int kr = li >> 4;                                                  \
      const int kc = ((li & 15) * 16) ^ ((kr & 7) << 4);                       \
      GLOAD16(kt0 + kr * 256 + kc, Kd + li * 16);                              \
      const int vd = li >> 3;                                                  \
      const int vc = ((li & 7) * 16) ^ ((vd & 7) << 4);                        \
      GLOAD16(vt0 + (size_t)vd * 8192 + vc, Vd + li * 16);                     \
    }                                                                          \
  }

  ATTN_STAGE(0, 0);
  for (int t = 0; t < 32; ++t) {
    const int cur = t & 1;
    if (t < 31) {
      ATTN_STAGE((t + 1) * 64, cur ^ 1);
      asm volatile("s_waitcnt vmcnt(4)" ::: "memory");  // tile t landed; t+1 in flight
    } else {
      asm volatile("s_waitcnt vmcnt(0)" ::: "memory");
    }
    __builtin_amdgcn_sched_barrier(0);
    __builtin_amdgcn_s_barrier();

    // S^T = K Q^T : lane (g,cc) holds S[key = n4*16+g*4+r][q = w*16+cc]
    const char* kcur = (const char*)(Ks[cur]);
    const int sw = (cc & 7) << 4;
    f32x4 sf[4] = {vzero, vzero, vzero, vzero};
    __builtin_amdgcn_s_setprio(1);
#pragma unroll
    for (int kk = 0; kk < 4; kk++) {
      const int ko = (kk * 64 + g * 16) ^ sw;
      bf16x8 kf0 = *(const bf16x8*)(kcur + (cc)*256 + ko);
      bf16x8 kf1 = *(const bf16x8*)(kcur + (16 + cc) * 256 + ko);
      bf16x8 kf2 = *(const bf16x8*)(kcur + (32 + cc) * 256 + ko);
      bf16x8 kf3 = *(const bf16x8*)(kcur + (48 + cc) * 256 + ko);
      sf[0] = __builtin_amdgcn_mfma_f32_16x16x32_bf16(kf0, qf[kk], sf[0], 0, 0, 0);
      sf[1] = __builtin_amdgcn_mfma_f32_16x16x32_bf16(kf1, qf[kk], sf[1], 0, 0, 0);
      sf[2] = __builtin_amdgcn_mfma_f32_16x16x32_bf16(kf2, qf[kk], sf[2], 0, 0, 0);
      sf[3] = __builtin_amdgcn_mfma_f32_16x16x32_bf16(kf3, qf[kk], sf[3], 0, 0, 0);
    }
    __builtin_amdgcn_s_setprio(0);

    // lane-local online softmax (16 keys/lane, reduce over 4-lane g-group)
    float tm = fmaxf(fmaxf(fmaxf(sf[0][0], sf[0][1]), fmaxf(sf[0][2], sf[0][3])),
                     fmaxf(fmaxf(sf[1][0], sf[1][1]), fmaxf(sf[1][2], sf[1][3])));
    tm = fmaxf(tm, fmaxf(fmaxf(fmaxf(sf[2][0], sf[2][1]), fmaxf(sf[2][2], sf[2][3])),
                         fmaxf(fmaxf(sf[3][0], sf[3][1]), fmaxf(sf[3][2], sf[3][3]))));
    tm = fmaxf(tm, __shfl_xor(tm, 16));
    tm = fmaxf(tm, __shfl_xor(tm, 32));
    if (__any(tm > mloc + 8.0f)) {             // defer-max (T13, THR=8 log2 units)
      const float mn = fmaxf(mloc, tm);
      const float sc = __builtin_amdgcn_exp2f(mloc - mn);
      mloc = mn;
      lloc *= sc;
      f32x4 scv;
#pragma unroll
      for (int r = 0; r < 4; r++) scv[r] = __shfl(sc, gbase + r);
#pragma unroll
      for (int d4 = 0; d4 < 8; d4++) acc[d4] *= scv;
    }
    float rs = 0.f;
#pragma unroll
    for (int n4 = 0; n4 < 4; n4++) {
      const float p0 = __builtin_amdgcn_exp2f(sf[n4][0] - mloc);
      const float p1 = __builtin_amdgcn_exp2f(sf[n4][1] - mloc);
      const float p2 = __builtin_amdgcn_exp2f(sf[n4][2] - mloc);
      const float p3 = __builtin_amdgcn_exp2f(sf[n4][3] - mloc);
      rs += (p0 + p1) + (p2 + p3);
      unsigned lo, hi;
      asm("v_cvt_pk_bf16_f32 %0, %1, %2" : "=v"(lo) : "v"(p0), "v"(p1));
      asm("v_cvt_pk_bf16_f32 %0, %1, %2" : "=v"(hi) : "v"(p2), "v"(p3));
      uint2 pv_; pv_.x = lo; pv_.y = hi;
      *(uint2*)(Pb + ((n4 * 32 + g * 8) ^ psw)) = pv_;   // P[q=cc][n4*16+g*4 ..+3]
    }
    rs += __shfl_xor(rs, 16);
    rs += __shfl_xor(rs, 32);
    lloc += rs;

    // O += P V   (A = P[q][k] from Ps, B = V^T from Vs)
    const char* vcur = (const char*)(Vs[cur]);
    __builtin_amdgcn_s_setprio(1);
#pragma unroll
    for (int ks = 0; ks < 2; ks++) {
      bf16x8 pf = *(const bf16x8*)(Pb + ((ks * 64 + g * 16) ^ psw));
#pragma unroll
      for (int d4 = 0; d4 < 8; d4++) {
        const int dd = d4 * 16 + cc;
        bf16x8 vf = *(const bf16x8*)(vcur + dd * 128 +
                                     ((ks * 64 + g * 16) ^ ((dd & 7) << 4)));
        acc[d4] = __builtin_amdgcn_mfma_f32_16x16x32_bf16(pf, vf, acc[d4], 0, 0, 0);
      }
    }
    __builtin_amdgcn_s_setprio(0);

    asm volatile("s_waitcnt lgkmcnt(0)" ::: "memory");  // reads done before overwrite
    __builtin_amdgcn_sched_barrier(0);
    __builtin_amdgcn_s_barrier();
  }
#undef ATTN_STAGE

  const float invl = __builtin_amdgcn_rcpf(lloc);
  float ir[4];
#pragma unroll
  for (int r = 0; r < 4; r++) ir[r] = __shfl(invl, gbase + r);
  unsigned short* Ob = O + (size_t)(b * 2048 + q0 + w * 16) * 2048 + h * 128;
#pragma unroll
  for (int d4 = 0; d4 < 8; d4++)
#pragma unroll
    for (int r = 0; r < 4; r++)
      Ob[(size_t)(g * 4 + r) * 2048 + d4 * 16 + cc] = f2bf(acc[d4][r] * ir[r]);
}

// ---------------------------------------------------------------------------
extern "C" void kernel_launch(void* const* d_in, const int* in_sizes, int n_in,
                              void* d_out, int out_size, void* d_ws, size_t ws_size,
                              hipStream_t stream) {
  const float* x     = (const float*)d_in[0];
  const float* q_w   = (const float*)d_in[1];
  const float* q_b   = (const float*)d_in[2];
  const float* k_w   = (const float*)d_in[3];
  const float* k_b   = (const float*)d_in[4];
  const float* v_w   = (const float*)d_in[5];
  const float* v_b   = (const float*)d_in[6];
  const float* o_w   = (const float*)d_in[7];
  const float* o_b   = (const float*)d_in[8];
  const float* nqw   = (const float*)d_in[9];
  const float* nkw   = (const float*)d_in[10];
  const float* freqs = (const float*)d_in[11];
  const int* inner_t = (const int*)d_in[14];

  const size_t NEED = (size_t)112 << 20;
  if (ws_size < NEED) return;

  char* ws = (char*)d_ws;
  unsigned short* xb   = (unsigned short*)(ws);                      // 16MB (later Q)
  unsigned short* WqkT = (unsigned short*)(ws + ((size_t)16 << 20)); // 16MB (later O)
  unsigned short* WvT  = (unsigned short*)(ws + ((size_t)32 << 20)); // 8MB
  unsigned short* WoT  = (unsigned short*)(ws + ((size_t)40 << 20)); // 8MB
  unsigned short* Yqk  = (unsigned short*)(ws + ((size_t)48 << 20)); // 32MB
  unsigned short* Vt   = (unsigned short*)(ws + ((size_t)80 << 20)); // 16MB
  unsigned short* Kr   = (unsigned short*)(ws + ((size_t)96 << 20)); // 16MB
  unsigned short* Qr   = xb;     // reuse: xb dead after V GEMM
  unsigned short* Orow = WqkT;   // reuse: WqkT dead after Yqk GEMM

  // fused: x convert + 4 weight transposes (1 launch)
  k_prep<<<8192, 256, 0, stream>>>(x, xb, q_w, k_w, v_w, o_w, WqkT, WvT, WoT);
  // Yqk[b*S+s][0:2048]=x@q_w, [2048:4096]=x@k_w  (256 wgs, 8-phase 256^2)
  k_gemm_yqk<<<256, 512, 0, stream>>>(xb, WqkT, Yqk);
  // Vt[h*128+d][b*S+s] = (x@v_w)^T + v_b[row]  (256 wgs, 8-phase 256x128)
  k_gemm_n128<0, 1><<<256, 512, 0, stream>>>(WvT, xb, Vt, v_b, 4096, 2048);
  k_qk_epi<<<4096, 256, 0, stream>>>(Yqk, q_b, k_b, nqw, nkw, freqs, inner_t, Qr, Kr);
  k_attn<<<512, 512, 0, stream>>>(Qr, Kr, Vt, Orow);
  // out = O @ o_w + o_b  (f32, 256 wgs, 8-phase 256x128)
  k_gemm_n128<1, 0><<<256, 512, 0, stream>>>(Orow, WoT, (float*)d_out, o_b, 2048, 2048);
}

// Round 12
// 292.025 us; speedup vs baseline: 1.1335x; 1.1335x over previous
//
#include <hip/hip_runtime.h>

// ---------------------------------------------------------------------------
// SelfAttention: x -> QKV proj -> RMSNorm -> RoPE -> softmax attn -> out proj
// B=2 S=2048 DIM=2048 NH=16 HD=128  (all shapes hard-coded)
// ---------------------------------------------------------------------------

typedef __attribute__((ext_vector_type(8))) short bf16x8;
typedef __attribute__((ext_vector_type(4))) float f32x4;

__device__ __forceinline__ unsigned short f2bf(float f) {
  unsigned int u = __builtin_bit_cast(unsigned int, f);
  u = (u + 0x7FFFu + ((u >> 16) & 1u)) >> 16;  // RNE
  return (unsigned short)u;
}
__device__ __forceinline__ float bf2f(unsigned short h) {
  unsigned int u = ((unsigned int)h) << 16;
  return __builtin_bit_cast(float, u);
}

#define GLOAD16(gp, lp)                                                        \
  __builtin_amdgcn_global_load_lds(                                            \
      (__attribute__((address_space(1))) void*)(gp),                           \
      (__attribute__((address_space(3))) void*)(lp), 16, 0, 0)

// ---------------- fused prep: x f32->bf16 convert + 4 weight transposes -----
__global__ __launch_bounds__(256) void k_prep(const float* __restrict__ x,
                                              unsigned short* __restrict__ xb,
                                              const float* __restrict__ qw,
                                              const float* __restrict__ kw,
                                              const float* __restrict__ vw,
                                              const float* __restrict__ ow,
                                              unsigned short* __restrict__ qkT,
                                              unsigned short* __restrict__ vT,
                                              unsigned short* __restrict__ oT) {
  const int bid = blockIdx.x;
  const int tid = threadIdx.x;
  if (bid >= 4096) {
    const int i = (bid - 4096) * 256 + tid;    // 4096*256 = 1,048,576 = n/8
    const float4* p = (const float4*)x + (size_t)i * 2;
    float4 a = p[0], b = p[1];
    bf16x8 v;
    v[0] = (short)f2bf(a.x); v[1] = (short)f2bf(a.y);
    v[2] = (short)f2bf(a.z); v[3] = (short)f2bf(a.w);
    v[4] = (short)f2bf(b.x); v[5] = (short)f2bf(b.y);
    v[6] = (short)f2bf(b.z); v[7] = (short)f2bf(b.w);
    *(bf16x8*)(xb + (size_t)i * 8) = v;
    return;
  }
  __shared__ float tile[64][65];
  const int mat = bid >> 10, t10 = bid & 1023;
  const float* in = (mat == 0) ? qw : (mat == 1) ? kw : (mat == 2) ? vw : ow;
  unsigned short* out = (mat == 0) ? qkT
                      : (mat == 1) ? (qkT + (size_t)2048 * 2048)
                      : (mat == 2) ? vT : oT;
  const int r0 = (t10 >> 5) * 64, c0 = (t10 & 31) * 64;
#pragma unroll
  for (int i = 0; i < 4; i++) {
    const int fi = tid + i * 256;
    const int row = fi >> 4, c4 = fi & 15;
    float4 v = *(const float4*)(in + (size_t)(r0 + row) * 2048 + c0 + c4 * 4);
    tile[row][c4 * 4 + 0] = v.x; tile[row][c4 * 4 + 1] = v.y;
    tile[row][c4 * 4 + 2] = v.z; tile[row][c4 * 4 + 3] = v.w;
  }
  __syncthreads();
#pragma unroll
  for (int i = 0; i < 2; i++) {
    const int oi = tid + i * 256;
    const int c = oi >> 3, r8 = oi & 7;
    bf16x8 o;
#pragma unroll
    for (int j = 0; j < 8; j++) o[j] = (short)f2bf(tile[r8 * 8 + j][c]);
    *(bf16x8*)(out + (size_t)(c0 + c) * 2048 + r0 + r8 * 8) = o;
  }
}

// ---------------- 128x128 GEMM, BK=64 + XOR swizzle (R12) -------------------
// m97 structure (2-barrier, 3 blocks/CU) but BK=64: half the barrier pairs.
// LDS 32KB. Linear [128][64] would be a 16-way read conflict (row stride
// 128B bank-aligned) -> yqk-style store/read XOR swizzle (conflict-free).
template <int OUTF32, int BIASMODE>
__global__ __launch_bounds__(256) void k_gemm(const unsigned short* __restrict__ A,
                                              const unsigned short* __restrict__ BT,
                                              void* __restrict__ Cout,
                                              const float* __restrict__ bias,
                                              int M, int N, int K) {
  __shared__ unsigned short As[128 * 64];
  __shared__ unsigned short Bs[128 * 64];
  const int tid = threadIdx.x;
  const int lane = tid & 63, w = tid >> 6;
  const int g = lane >> 4, cc = lane & 15;
  const int gx = gridDim.x;
  int id = blockIdx.y * gx + blockIdx.x;
  const int tot = gx * gridDim.y;
  id = (id & 7) * (tot >> 3) + (id >> 3);      // XCD-contiguous chunks
  const int n0 = (id % gx) * 128, m0 = (id / gx) * 128;
  const int wm = (w >> 1) * 64, wn = (w & 1) * 64;
  const int swz = (cc & 7) << 4;
  f32x4 acc[4][4] = {};
  const unsigned short* Ab = A + (size_t)m0 * K;
  const unsigned short* Bb = BT + (size_t)n0 * K;
  for (int kt = 0; kt < K; kt += 64) {
#pragma unroll
    for (int i = 0; i < 4; i++) {
      const int li = i * 256 + tid;            // 1024 chunks of 16B per buffer
      const int r = li >> 3;
      const int c16 = (li & 7) ^ (r & 7);      // inverse-swizzled global source
      GLOAD16(Ab + (size_t)r * K + kt + c16 * 8, (char*)As + li * 16);
      GLOAD16(Bb + (size_t)r * K + kt + c16 * 8, (char*)Bs + li * 16);
    }
    __syncthreads();
    bf16x8 af[4][2], bfr[4][2];
#pragma unroll
    for (int m4 = 0; m4 < 4; m4++)
#pragma unroll
      for (int kk = 0; kk < 2; kk++)
        af[m4][kk] = *(const bf16x8*)((char*)As + (wm + m4 * 16 + cc) * 128 +
                                      ((kk * 64 + g * 16) ^ swz));
#pragma unroll
    for (int n4 = 0; n4 < 4; n4++)
#pragma unroll
      for (int kk = 0; kk < 2; kk++)
        bfr[n4][kk] = *(const bf16x8*)((char*)Bs + (wn + n4 * 16 + cc) * 128 +
                                       ((kk * 64 + g * 16) ^ swz));
#pragma unroll
    for (int kk = 0; kk < 2; kk++)
#pragma unroll
      for (int m4 = 0; m4 < 4; m4++)
#pragma unroll
        for (int n4 = 0; n4 < 4; n4++)
          acc[m4][n4] = __builtin_amdgcn_mfma_f32_16x16x32_bf16(af[m4][kk], bfr[n4][kk],
                                                                acc[m4][n4], 0, 0, 0);
    __syncthreads();
  }
#pragma unroll
  for (int m4 = 0; m4 < 4; m4++)
#pragma unroll
    for (int n4 = 0; n4 < 4; n4++) {
      const int col = n0 + wn + n4 * 16 + cc;
#pragma unroll
      for (int r = 0; r < 4; r++) {
        const int row = m0 + wm + m4 * 16 + g * 4 + r;
        float v = acc[m4][n4][r];
        if (BIASMODE == 1) v += bias[row];
        if (BIASMODE == 2) v += bias[col];
        if (OUTF32)
          ((float*)Cout)[(size_t)row * N + col] = v;
        else
          ((unsigned short*)Cout)[(size_t)row * N + col] = f2bf(v);
      }
    }
}

// ---------------- shared staging helper (512-thread blocks) -----------------
__device__ __forceinline__ void stage_half(const unsigned short* __restrict__ src,
                                           int K, unsigned short* dst, int tid) {
#pragma unroll
  for (int j = 0; j < 2; j++) {
    const int li = tid + j * 512;
    const int r = li >> 3;
    const int c16 = (li & 7) ^ (r & 7);
    GLOAD16(src + (size_t)r * K + c16 * 8, (char*)dst + li * 16);
  }
}

// ---------------- 256x256 8-phase GEMM (T2+T3+T4+T5) -- Yqk only ------------
__global__ __launch_bounds__(512, 2) void k_gemm_yqk(const unsigned short* __restrict__ A,
                                                     const unsigned short* __restrict__ BT,
                                                     unsigned short* __restrict__ Cout) {
  __shared__ unsigned short As[2][256 * 64];
  __shared__ unsigned short Bs[2][256 * 64];
  const int tid = threadIdx.x;
  const int lane = tid & 63, w = tid >> 6;
  const int g = lane >> 4, cc = lane & 15;
  const int wm = (w >> 2) * 128, wn = (w & 3) * 64;
  const int swz = (cc & 7) << 4;
  const int N = 4096, K = 2048;
  int id = blockIdx.x;
  id = (id & 7) * 32 + (id >> 3);              // 256 wgs -> 32/XCD contiguous
  const int m0 = (id >> 4) * 256, n0 = (id & 15) * 256;
  f32x4 acc[8][4] = {};
  const int T = K >> 6;                        // 32 K-tiles

  stage_half(BT + (size_t)n0 * K, K, Bs[0], tid);
  stage_half(A + (size_t)m0 * K, K, As[0], tid);
  stage_half(BT + (size_t)(n0 + 128) * K, K, Bs[0] + 8192, tid);
  stage_half(A + (size_t)(m0 + 128) * K, K, As[0] + 8192, tid);
  stage_half(BT + (size_t)n0 * K + 64, K, Bs[1], tid);
  stage_half(A + (size_t)m0 * K + 64, K, As[1], tid);
  asm volatile("s_waitcnt vmcnt(4)" ::: "memory");
  __builtin_amdgcn_s_barrier();

  for (int t = 0; t < T; ++t) {
    const int c = t & 1;
    const char* Ac = (const char*)As[c];
    const char* Bc = (const char*)Bs[c];
    bf16x8 ar[4][2], br[4][2];
    // -------- phase 1
#pragma unroll
    for (int m = 0; m < 4; m++)
#pragma unroll
      for (int kk = 0; kk < 2; kk++)
        ar[m][kk] = *(const bf16x8*)(Ac + (wm + m * 16 + cc) * 128 +
                                     ((kk * 64 + g * 16) ^ swz));
#pragma unroll
    for (int n = 0; n < 2; n++)
#pragma unroll
      for (int kk = 0; kk < 2; kk++)
        br[n][kk] = *(const bf16x8*)(Bc + (wn + n * 16 + cc) * 128 +
                                     ((kk * 64 + g * 16) ^ swz));
    stage_half(BT + (size_t)(n0 + 128) * K + ((t + 1) & (T - 1)) * 64, K,
               Bs[c ^ 1] + 8192, tid);
    __builtin_amdgcn_s_barrier();
    __builtin_amdgcn_sched_barrier(0);
    __builtin_amdgcn_s_setprio(1);
#pragma unroll
    for (int kk = 0; kk < 2; kk++)
#pragma unroll
      for (int m = 0; m < 4; m++)
#pragma unroll
        for (int n = 0; n < 2; n++)
          acc[m][n] = __builtin_amdgcn_mfma_f32_16x16x32_bf16(ar[m][kk], br[n][kk],
                                                              acc[m][n], 0, 0, 0);
    __builtin_amdgcn_s_setprio(0);
    __builtin_amdgcn_s_barrier();
    __builtin_amdgcn_sched_barrier(0);
    // -------- phase 2
#pragma unroll
    for (int n = 2; n < 4; n++)
#pragma unroll
      for (int kk = 0; kk < 2; kk++)
        br[n][kk] = *(const bf16x8*)(Bc + (wn + n * 16 + cc) * 128 +
                                     ((kk * 64 + g * 16) ^ swz));
    stage_half(A + (size_t)(m0 + 128) * K + ((t + 1) & (T - 1)) * 64, K,
               As[c ^ 1] + 8192, tid);
    __builtin_amdgcn_s_barrier();
    __builtin_amdgcn_sched_barrier(0);
    __builtin_amdgcn_s_setprio(1);
#pragma unroll
    for (int kk = 0; kk < 2; kk++)
#pragma unroll
      for (int m = 0; m < 4; m++)
#pragma unroll
        for (int n = 2; n < 4; n++)
          acc[m][n] = __builtin_amdgcn_mfma_f32_16x16x32_bf16(ar[m][kk], br[n][kk],
                                                              acc[m][n], 0, 0, 0);
    __builtin_amdgcn_s_setprio(0);
    __builtin_amdgcn_s_barrier();
    __builtin_amdgcn_sched_barrier(0);
    // -------- phase 3
#pragma unroll
    for (int m = 0; m < 4; m++)
#pragma unroll
      for (int kk = 0; kk < 2; kk++)
        ar[m][kk] = *(const bf16x8*)(Ac + (wm + (m + 4) * 16 + cc) * 128 +
                                     ((kk * 64 + g * 16) ^ swz));
    stage_half(BT + (size_t)n0 * K + ((t + 2) & (T - 1)) * 64, K, Bs[c], tid);
    __builtin_amdgcn_s_barrier();
    __builtin_amdgcn_sched_barrier(0);
    __builtin_amdgcn_s_setprio(1);
#pragma unroll
    for (int kk = 0; kk < 2; kk++)
#pragma unroll
      for (int m = 0; m < 4; m++)
#pragma unroll
        for (int n = 0; n < 2; n++)
          acc[m + 4][n] = __builtin_amdgcn_mfma_f32_16x16x32_bf16(ar[m][kk], br[n][kk],
                                                                  acc[m + 4][n], 0, 0, 0);
    __builtin_amdgcn_s_setprio(0);
    __builtin_amdgcn_s_barrier();
    __builtin_amdgcn_sched_barrier(0);
    // -------- phase 4
    stage_half(A + (size_t)m0 * K + ((t + 2) & (T - 1)) * 64, K, As[c], tid);
    __builtin_amdgcn_s_setprio(1);
#pragma unroll
    for (int kk = 0; kk < 2; kk++)
#pragma unroll
      for (int m = 0; m < 4; m++)
#pragma unroll
        for (int n = 2; n < 4; n++)
          acc[m + 4][n] = __builtin_amdgcn_mfma_f32_16x16x32_bf16(ar[m][kk], br[n][kk],
                                                                  acc[m + 4][n], 0, 0, 0);
    __builtin_amdgcn_s_setprio(0);
    if (t < T - 2)
      asm volatile("s_waitcnt vmcnt(4)" ::: "memory");
    else
      asm volatile("s_waitcnt vmcnt(0)" ::: "memory");
    __builtin_amdgcn_sched_barrier(0);
    __builtin_amdgcn_s_barrier();
    __builtin_amdgcn_sched_barrier(0);
  }

#pragma unroll
  for (int mi = 0; mi < 8; mi++)
#pragma unroll
    for (int n = 0; n < 4; n++) {
      const int col = n0 + wn + n * 16 + cc;
#pragma unroll
      for (int j = 0; j < 4; j++) {
        const int row = m0 + wm + mi * 16 + g * 4 + j;
        Cout[(size_t)row * N + col] = f2bf(acc[mi][n][j]);
      }
    }
}

// ---------------- QK epilogue: bias + RMSNorm + RoPE -> Q,K [b,h,s,d] ------
__global__ __launch_bounds__(256) void k_qk_epi(const unsigned short* __restrict__ Yqk, // [4096][4096]
                                                const float* __restrict__ q_b,
                                                const float* __restrict__ k_b,
                                                const float* __restrict__ nqw,
                                                const float* __restrict__ nkw,
                                                const float* __restrict__ freqs, // [1024][64][2]
                                                const int* __restrict__ inner_t, // [2][2]
                                                unsigned short* __restrict__ Q,
                                                unsigned short* __restrict__ K) {
  const int row = blockIdx.x;          // b*2048 + s
  const int b = row >> 11, s = row & 2047;
  const int t = threadIdx.x;
  const unsigned short* yr = Yqk + (size_t)row * 4096;
  bf16x8 yq = *(const bf16x8*)(yr + t * 8);
  bf16x8 yk = *(const bf16x8*)(yr + 2048 + t * 8);
  float4 qb0 = *(const float4*)(q_b + t * 8), qb1 = *(const float4*)(q_b + t * 8 + 4);
  float4 kb0 = *(const float4*)(k_b + t * 8), kb1 = *(const float4*)(k_b + t * 8 + 4);
  float q[8], k[8];
  q[0] = bf2f((unsigned short)yq[0]) + qb0.x; q[1] = bf2f((unsigned short)yq[1]) + qb0.y;
  q[2] = bf2f((unsigned short)yq[2]) + qb0.z; q[3] = bf2f((unsigned short)yq[3]) + qb0.w;
  q[4] = bf2f((unsigned short)yq[4]) + qb1.x; q[5] = bf2f((unsigned short)yq[5]) + qb1.y;
  q[6] = bf2f((unsigned short)yq[6]) + qb1.z; q[7] = bf2f((unsigned short)yq[7]) + qb1.w;
  k[0] = bf2f((unsigned short)yk[0]) + kb0.x; k[1] = bf2f((unsigned short)yk[1]) + kb0.y;
  k[2] = bf2f((unsigned short)yk[2]) + kb0.z; k[3] = bf2f((unsigned short)yk[3]) + kb0.w;
  k[4] = bf2f((unsigned short)yk[4]) + kb1.x; k[5] = bf2f((unsigned short)yk[5]) + kb1.y;
  k[6] = bf2f((unsigned short)yk[6]) + kb1.z; k[7] = bf2f((unsigned short)yk[7]) + kb1.w;
  float ssq = 0.f, ssk = 0.f;
#pragma unroll
  for (int j = 0; j < 8; j++) { ssq += q[j] * q[j]; ssk += k[j] * k[j]; }
#pragma unroll
  for (int off = 32; off; off >>= 1) {
    ssq += __shfl_xor(ssq, off);
    ssk += __shfl_xor(ssk, off);
  }
  __shared__ float red[8];
  const int w = t >> 6;
  if ((t & 63) == 0) { red[w] = ssq; red[4 + w] = ssk; }
  __syncthreads();
  const float sq = red[0] + red[1] + red[2] + red[3];
  const float sk = red[4] + red[5] + red[6] + red[7];
  const float rq = __builtin_amdgcn_rsqf(sq * (1.0f / 2048.0f) + 1e-6f);
  const float rk = __builtin_amdgcn_rsqf(sk * (1.0f / 2048.0f) + 1e-6f);
  float4 nq0 = *(const float4*)(nqw + t * 8), nq1 = *(const float4*)(nqw + t * 8 + 4);
  float4 nk0 = *(const float4*)(nkw + t * 8), nk1 = *(const float4*)(nkw + t * 8 + 4);
  q[0] *= rq * nq0.x; q[1] *= rq * nq0.y; q[2] *= rq * nq0.z; q[3] *= rq * nq0.w;
  q[4] *= rq * nq1.x; q[5] *= rq * nq1.y; q[6] *= rq * nq1.z; q[7] *= rq * nq1.w;
  k[0] *= rk * nk0.x; k[1] *= rk * nk0.y; k[2] *= rk * nk0.z; k[3] *= rk * nk0.w;
  k[4] *= rk * nk1.x; k[5] *= rk * nk1.y; k[6] *= rk * nk1.z; k[7] *= rk * nk1.w;
  // RoPE: s -> (f,h,w) with HW grid 8x16x16, pairs are adjacent elems
  const int f = s >> 8, hh = (s >> 4) & 15, ww = s & 15;
  const int it0 = inner_t[b * 2], it1 = inner_t[b * 2 + 1];
  const int trow = ((f >= it0) + (f >= it0 + it1)) * 4 + f;  // SHIFT=4
#pragma unroll
  for (int jj = 0; jj < 4; jj++) {
    const int c = (t * 4 + jj) & 63;              // pair idx within head (C=64)
    const int fr = (c < 22) ? trow : ((c < 43) ? hh : ww);  // CT=22, CT+CH=43
    const float cr = freqs[((size_t)fr * 64 + c) * 2];
    const float ci = freqs[((size_t)fr * 64 + c) * 2 + 1];
    float a = q[2 * jj], bb = q[2 * jj + 1];
    q[2 * jj] = a * cr - bb * ci; q[2 * jj + 1] = a * ci + bb * cr;
    a = k[2 * jj]; bb = k[2 * jj + 1];
    k[2 * jj] = a * cr - bb * ci; k[2 * jj + 1] = a * ci + bb * cr;
  }
  // fold attn scale and log2(e) into Q (softmax done in exp2 domain)
  const float QSCALE = 0.08838834764831845f * 1.4426950408889634f;
  bf16x8 oq, ok;
#pragma unroll
  for (int j = 0; j < 8; j++) {
    oq[j] = (short)f2bf(q[j] * QSCALE);
    ok[j] = (short)f2bf(k[j]);
  }
  const int head = t >> 4, d0 = (t & 15) * 8;
  const size_t off = ((size_t)(b * 16 + head) * 2048 + s) * 128 + d0;
  *(bf16x8*)(Q + off) = oq;
  *(bf16x8*)(K + off) = ok;
}

// ---------------- flash attention (R6/R10 version, known-good) --------------
__global__ __launch_bounds__(512, 4) void k_attn(const unsigned short* __restrict__ Q,
                                                 const unsigned short* __restrict__ K,
                                                 const unsigned short* __restrict__ V,
                                                 unsigned short* __restrict__ O) {
  __shared__ unsigned short Ks[2][64 * 128];   // [key][d], byte ^= (key&7)<<4
  __shared__ unsigned short Vs[2][128 * 64];   // [d][key], byte ^= (d&7)<<4
  __shared__ unsigned short Ps[8 * 16 * 64];   // per-wave P [q][key], byte ^= (q&7)<<4
  const int tid = threadIdx.x;
  const int lane = tid & 63, w = tid >> 6;
  const int g = lane >> 4, cc = lane & 15;
  const int orig = blockIdx.x;                 // 512 blocks flat
  const int lid = (orig & 7) * 64 + (orig >> 3);  // XCD gets 64 consecutive lids
  const int bh = lid >> 4;                     // 4 full heads per XCD
  const int q0 = (lid & 15) * 128;
  const int b = bh >> 4, h = bh & 15;

  const unsigned short* Qb = Q + ((size_t)bh * 2048 + q0 + w * 16 + cc) * 128;
  bf16x8 qf[4];
#pragma unroll
  for (int kk = 0; kk < 4; kk++) qf[kk] = *(const bf16x8*)(Qb + kk * 32 + g * 8);

  const char* kbase = (const char*)(K + (size_t)bh * 2048 * 128);
  const char* vbase = (const char*)V + ((size_t)h * 128 * 4096 + (size_t)b * 2048) * 2;

  f32x4 acc[8] = {};
  float mloc = -3.0e38f, lloc = 0.f;           // per-lane stats for q = w*16+cc
  char* Pb = (char*)Ps + w * 2048 + cc * 128;
  const int psw = (cc & 7) << 4;
  const int gbase = (lane & 48) | (((lane >> 4) & 3) << 2);  // lane g*16 + g*4
  const f32x4 vzero = {0.f, 0.f, 0.f, 0.f};

#define ATTN_STAGE(s0, bi)                                                     \
  {                                                                            \
    const char* kt0 = kbase + (size_t)(s0) * 256;                              \
    const char* vt0 = vbase + (size_t)(s0) * 2;                                \
    char* Kd = (char*)(Ks[bi]);                                                \
    char* Vd = (char*)(Vs[bi]);                                                \
    _Pragma("unroll") for (int i = 0; i < 2; i++) {                            \
      const int li = i * 512 + tid;                                            \
      const int kr = li >> 4;                                                  \
      const int kc = ((li & 15) * 16) ^ ((kr & 7) << 4);                       \
      GLOAD16(kt0 + kr * 256 + kc, Kd + li * 16);                              \
      const int vd = li >> 3;                                                  \
      const int vc = ((li & 7) * 16) ^ ((vd & 7) << 4);                        \
      GLOAD16(vt0 + (size_t)vd * 8192 + vc, Vd + li * 16);                     \
    }                                                                          \
  }

  ATTN_STAGE(0, 0);
  for (int t = 0; t < 32; ++t) {
    const int cur = t & 1;
    if (t < 31) {
      ATTN_STAGE((t + 1) * 64, cur ^ 1);
      asm volatile("s_waitcnt vmcnt(4)" ::: "memory");  // tile t landed; t+1 in flight
    } else {
      asm volatile("s_waitcnt vmcnt(0)" ::: "memory");
    }
    __builtin_amdgcn_sched_barrier(0);
    __builtin_amdgcn_s_barrier();

    // S^T = K Q^T : lane (g,cc) holds S[key = n4*16+g*4+r][q = w*16+cc]
    const char* kcur = (const char*)(Ks[cur]);
    const int sw = (cc & 7) << 4;
    f32x4 sf[4] = {vzero, vzero, vzero, vzero};
    __builtin_amdgcn_s_setprio(1);
#pragma unroll
    for (int kk = 0; kk < 4; kk++) {
      const int ko = (kk * 64 + g * 16) ^ sw;
      bf16x8 kf0 = *(const bf16x8*)(kcur + (cc)*256 + ko);
      bf16x8 kf1 = *(const bf16x8*)(kcur + (16 + cc) * 256 + ko);
      bf16x8 kf2 = *(const bf16x8*)(kcur + (32 + cc) * 256 + ko);
      bf16x8 kf3 = *(const bf16x8*)(kcur + (48 + cc) * 256 + ko);
      sf[0] = __builtin_amdgcn_mfma_f32_16x16x32_bf16(kf0, qf[kk], sf[0], 0, 0, 0);
      sf[1] = __builtin_amdgcn_mfma_f32_16x16x32_bf16(kf1, qf[kk], sf[1], 0, 0, 0);
      sf[2] = __builtin_amdgcn_mfma_f32_16x16x32_bf16(kf2, qf[kk], sf[2], 0, 0, 0);
      sf[3] = __builtin_amdgcn_mfma_f32_16x16x32_bf16(kf3, qf[kk], sf[3], 0, 0, 0);
    }
    __builtin_amdgcn_s_setprio(0);

    // lane-local online softmax (16 keys/lane, reduce over 4-lane g-group)
    float tm = fmaxf(fmaxf(fmaxf(sf[0][0], sf[0][1]), fmaxf(sf[0][2], sf[0][3])),
                     fmaxf(fmaxf(sf[1][0], sf[1][1]), fmaxf(sf[1][2], sf[1][3])));
    tm = fmaxf(tm, fmaxf(fmaxf(fmaxf(sf[2][0], sf[2][1]), fmaxf(sf[2][2], sf[2][3])),
                         fmaxf(fmaxf(sf[3][0], sf[3][1]), fmaxf(sf[3][2], sf[3][3]))));
    tm = fmaxf(tm, __shfl_xor(tm, 16));
    tm = fmaxf(tm, __shfl_xor(tm, 32));
    if (__any(tm > mloc + 8.0f)) {             // defer-max (T13, THR=8 log2 units)
      const float mn = fmaxf(mloc, tm);
      const float sc = __builtin_amdgcn_exp2f(mloc - mn);
      mloc = mn;
      lloc *= sc;
      f32x4 scv;
#pragma unroll
      for (int r = 0; r < 4; r++) scv[r] = __shfl(sc, gbase + r);
#pragma unroll
      for (int d4 = 0; d4 < 8; d4++) acc[d4] *= scv;
    }
    float rs = 0.f;
#pragma unroll
    for (int n4 = 0; n4 < 4; n4++) {
      const float p0 = __builtin_amdgcn_exp2f(sf[n4][0] - mloc);
      const float p1 = __builtin_amdgcn_exp2f(sf[n4][1] - mloc);
      const float p2 = __builtin_amdgcn_exp2f(sf[n4][2] - mloc);
      const float p3 = __builtin_amdgcn_exp2f(sf[n4][3] - mloc);
      rs += (p0 + p1) + (p2 + p3);
      unsigned lo, hi;
      asm("v_cvt_pk_bf16_f32 %0, %1, %2" : "=v"(lo) : "v"(p0), "v"(p1));
      asm("v_cvt_pk_bf16_f32 %0, %1, %2" : "=v"(hi) : "v"(p2), "v"(p3));
      uint2 pv_; pv_.x = lo; pv_.y = hi;
      *(uint2*)(Pb + ((n4 * 32 + g * 8) ^ psw)) = pv_;   // P[q=cc][n4*16+g*4 ..+3]
    }
    rs += __shfl_xor(rs, 16);
    rs += __shfl_xor(rs, 32);
    lloc += rs;

    // O += P V   (A = P[q][k] from Ps, B = V^T from Vs)
    const char* vcur = (const char*)(Vs[cur]);
    __builtin_amdgcn_s_setprio(1);
#pragma unroll
    for (int ks = 0; ks < 2; ks++) {
      bf16x8 pf = *(const bf16x8*)(Pb + ((ks * 64 + g * 16) ^ psw));
#pragma unroll
      for (int d4 = 0; d4 < 8; d4++) {
        const int dd = d4 * 16 + cc;
        bf16x8 vf = *(const bf16x8*)(vcur + dd * 128 +
                                     ((ks * 64 + g * 16) ^ ((dd & 7) << 4)));
        acc[d4] = __builtin_amdgcn_mfma_f32_16x16x32_bf16(pf, vf, acc[d4], 0, 0, 0);
      }
    }
    __builtin_amdgcn_s_setprio(0);

    asm volatile("s_waitcnt lgkmcnt(0)" ::: "memory");  // reads done before overwrite
    __builtin_amdgcn_sched_barrier(0);
    __builtin_amdgcn_s_barrier();
  }
#undef ATTN_STAGE

  const float invl = __builtin_amdgcn_rcpf(lloc);
  float ir[4];
#pragma unroll
  for (int r = 0; r < 4; r++) ir[r] = __shfl(invl, gbase + r);
  unsigned short* Ob = O + (size_t)(b * 2048 + q0 + w * 16) * 2048 + h * 128;
#pragma unroll
  for (int d4 = 0; d4 < 8; d4++)
#pragma unroll
    for (int r = 0; r < 4; r++)
      Ob[(size_t)(g * 4 + r) * 2048 + d4 * 16 + cc] = f2bf(acc[d4][r] * ir[r]);
}

// ---------------------------------------------------------------------------
extern "C" void kernel_launch(void* const* d_in, const int* in_sizes, int n_in,
                              void* d_out, int out_size, void* d_ws, size_t ws_size,
                              hipStream_t stream) {
  const float* x     = (const float*)d_in[0];
  const float* q_w   = (const float*)d_in[1];
  const float* q_b   = (const float*)d_in[2];
  const float* k_w   = (const float*)d_in[3];
  const float* k_b   = (const float*)d_in[4];
  const float* v_w   = (const float*)d_in[5];
  const float* v_b   = (const float*)d_in[6];
  const float* o_w   = (const float*)d_in[7];
  const float* o_b   = (const float*)d_in[8];
  const float* nqw   = (const float*)d_in[9];
  const float* nkw   = (const float*)d_in[10];
  const float* freqs = (const float*)d_in[11];
  const int* inner_t = (const int*)d_in[14];

  const size_t NEED = (size_t)112 << 20;
  if (ws_size < NEED) return;

  char* ws = (char*)d_ws;
  unsigned short* xb   = (unsigned short*)(ws);                      // 16MB (later Q)
  unsigned short* WqkT = (unsigned short*)(ws + ((size_t)16 << 20)); // 16MB (later O)
  unsigned short* WvT  = (unsigned short*)(ws + ((size_t)32 << 20)); // 8MB
  unsigned short* WoT  = (unsigned short*)(ws + ((size_t)40 << 20)); // 8MB
  unsigned short* Yqk  = (unsigned short*)(ws + ((size_t)48 << 20)); // 32MB
  unsigned short* Vt   = (unsigned short*)(ws + ((size_t)80 << 20)); // 16MB
  unsigned short* Kr   = (unsigned short*)(ws + ((size_t)96 << 20)); // 16MB
  unsigned short* Qr   = xb;     // reuse: xb dead after V GEMM
  unsigned short* Orow = WqkT;   // reuse: WqkT dead after Yqk GEMM

  // fused: x convert + 4 weight transposes (1 launch)
  k_prep<<<8192, 256, 0, stream>>>(x, xb, q_w, k_w, v_w, o_w, WqkT, WvT, WoT);
  // Yqk[b*S+s][0:2048]=x@q_w, [2048:4096]=x@k_w  (256 wgs, 8-phase 256^2)
  k_gemm_yqk<<<256, 512, 0, stream>>>(xb, WqkT, Yqk);
  // Vt[h*128+d][b*S+s] = (x@v_w)^T + v_b[row]  (BK=64 swizzled 128^2)
  k_gemm<0, 1><<<dim3(32, 16), 256, 0, stream>>>(WvT, xb, Vt, v_b, 2048, 4096, 2048);
  k_qk_epi<<<4096, 256, 0, stream>>>(Yqk, q_b, k_b, nqw, nkw, freqs, inner_t, Qr, Kr);
  k_attn<<<512, 512, 0, stream>>>(Qr, Kr, Vt, Orow);
  // out = O @ o_w + o_b  (f32, BK=64 swizzled 128^2)
  k_gemm<1, 2><<<dim3(16, 32), 256, 0, stream>>>(Orow, WoT, (float*)d_out, o_b, 4096, 2048, 2048);
}

// Round 13
// 289.852 us; speedup vs baseline: 1.1420x; 1.0075x over previous
//
#include <hip/hip_runtime.h>

// ---------------------------------------------------------------------------
// SelfAttention: x -> QKV proj -> RMSNorm -> RoPE -> softmax attn -> out proj
// B=2 S=2048 DIM=2048 NH=16 HD=128  (all shapes hard-coded)
// ---------------------------------------------------------------------------

typedef __attribute__((ext_vector_type(8))) short bf16x8;
typedef __attribute__((ext_vector_type(4))) float f32x4;

__device__ __forceinline__ unsigned short f2bf(float f) {
  unsigned int u = __builtin_bit_cast(unsigned int, f);
  u = (u + 0x7FFFu + ((u >> 16) & 1u)) >> 16;  // RNE
  return (unsigned short)u;
}
__device__ __forceinline__ float bf2f(unsigned short h) {
  unsigned int u = ((unsigned int)h) << 16;
  return __builtin_bit_cast(float, u);
}

#define GLOAD16(gp, lp)                                                        \
  __builtin_amdgcn_global_load_lds(                                            \
      (__attribute__((address_space(1))) void*)(gp),                           \
      (__attribute__((address_space(3))) void*)(lp), 16, 0, 0)

// ---------------- fused prep: x f32->bf16 convert + 4 weight transposes -----
__global__ __launch_bounds__(256) void k_prep(const float* __restrict__ x,
                                              unsigned short* __restrict__ xb,
                                              const float* __restrict__ qw,
                                              const float* __restrict__ kw,
                                              const float* __restrict__ vw,
                                              const float* __restrict__ ow,
                                              unsigned short* __restrict__ qkT,
                                              unsigned short* __restrict__ vT,
                                              unsigned short* __restrict__ oT) {
  const int bid = blockIdx.x;
  const int tid = threadIdx.x;
  if (bid >= 4096) {
    const int i = (bid - 4096) * 256 + tid;    // 4096*256 = 1,048,576 = n/8
    const float4* p = (const float4*)x + (size_t)i * 2;
    float4 a = p[0], b = p[1];
    bf16x8 v;
    v[0] = (short)f2bf(a.x); v[1] = (short)f2bf(a.y);
    v[2] = (short)f2bf(a.z); v[3] = (short)f2bf(a.w);
    v[4] = (short)f2bf(b.x); v[5] = (short)f2bf(b.y);
    v[6] = (short)f2bf(b.z); v[7] = (short)f2bf(b.w);
    *(bf16x8*)(xb + (size_t)i * 8) = v;
    return;
  }
  __shared__ float tile[64][65];
  const int mat = bid >> 10, t10 = bid & 1023;
  const float* in = (mat == 0) ? qw : (mat == 1) ? kw : (mat == 2) ? vw : ow;
  unsigned short* out = (mat == 0) ? qkT
                      : (mat == 1) ? (qkT + (size_t)2048 * 2048)
                      : (mat == 2) ? vT : oT;
  const int r0 = (t10 >> 5) * 64, c0 = (t10 & 31) * 64;
#pragma unroll
  for (int i = 0; i < 4; i++) {
    const int fi = tid + i * 256;
    const int row = fi >> 4, c4 = fi & 15;
    float4 v = *(const float4*)(in + (size_t)(r0 + row) * 2048 + c0 + c4 * 4);
    tile[row][c4 * 4 + 0] = v.x; tile[row][c4 * 4 + 1] = v.y;
    tile[row][c4 * 4 + 2] = v.z; tile[row][c4 * 4 + 3] = v.w;
  }
  __syncthreads();
#pragma unroll
  for (int i = 0; i < 2; i++) {
    const int oi = tid + i * 256;
    const int c = oi >> 3, r8 = oi & 7;
    bf16x8 o;
#pragma unroll
    for (int j = 0; j < 8; j++) o[j] = (short)f2bf(tile[r8 * 8 + j][c]);
    *(bf16x8*)(out + (size_t)(c0 + c) * 2048 + r0 + r8 * 8) = o;
  }
}

// ---------------- 128x128 GEMM, BK=64 + XOR swizzle (R12, proven) -----------
template <int OUTF32, int BIASMODE>
__global__ __launch_bounds__(256) void k_gemm(const unsigned short* __restrict__ A,
                                              const unsigned short* __restrict__ BT,
                                              void* __restrict__ Cout,
                                              const float* __restrict__ bias,
                                              int M, int N, int K) {
  __shared__ unsigned short As[128 * 64];
  __shared__ unsigned short Bs[128 * 64];
  const int tid = threadIdx.x;
  const int lane = tid & 63, w = tid >> 6;
  const int g = lane >> 4, cc = lane & 15;
  const int gx = gridDim.x;
  int id = blockIdx.y * gx + blockIdx.x;
  const int tot = gx * gridDim.y;
  id = (id & 7) * (tot >> 3) + (id >> 3);      // XCD-contiguous chunks
  const int n0 = (id % gx) * 128, m0 = (id / gx) * 128;
  const int wm = (w >> 1) * 64, wn = (w & 1) * 64;
  const int swz = (cc & 7) << 4;
  f32x4 acc[4][4] = {};
  const unsigned short* Ab = A + (size_t)m0 * K;
  const unsigned short* Bb = BT + (size_t)n0 * K;
  for (int kt = 0; kt < K; kt += 64) {
#pragma unroll
    for (int i = 0; i < 4; i++) {
      const int li = i * 256 + tid;            // 1024 chunks of 16B per buffer
      const int r = li >> 3;
      const int c16 = (li & 7) ^ (r & 7);      // inverse-swizzled global source
      GLOAD16(Ab + (size_t)r * K + kt + c16 * 8, (char*)As + li * 16);
      GLOAD16(Bb + (size_t)r * K + kt + c16 * 8, (char*)Bs + li * 16);
    }
    __syncthreads();
    bf16x8 af[4][2], bfr[4][2];
#pragma unroll
    for (int m4 = 0; m4 < 4; m4++)
#pragma unroll
      for (int kk = 0; kk < 2; kk++)
        af[m4][kk] = *(const bf16x8*)((char*)As + (wm + m4 * 16 + cc) * 128 +
                                      ((kk * 64 + g * 16) ^ swz));
#pragma unroll
    for (int n4 = 0; n4 < 4; n4++)
#pragma unroll
      for (int kk = 0; kk < 2; kk++)
        bfr[n4][kk] = *(const bf16x8*)((char*)Bs + (wn + n4 * 16 + cc) * 128 +
                                       ((kk * 64 + g * 16) ^ swz));
#pragma unroll
    for (int kk = 0; kk < 2; kk++)
#pragma unroll
      for (int m4 = 0; m4 < 4; m4++)
#pragma unroll
        for (int n4 = 0; n4 < 4; n4++)
          acc[m4][n4] = __builtin_amdgcn_mfma_f32_16x16x32_bf16(af[m4][kk], bfr[n4][kk],
                                                                acc[m4][n4], 0, 0, 0);
    __syncthreads();
  }
#pragma unroll
  for (int m4 = 0; m4 < 4; m4++)
#pragma unroll
    for (int n4 = 0; n4 < 4; n4++) {
      const int col = n0 + wn + n4 * 16 + cc;
#pragma unroll
      for (int r = 0; r < 4; r++) {
        const int row = m0 + wm + m4 * 16 + g * 4 + r;
        float v = acc[m4][n4][r];
        if (BIASMODE == 1) v += bias[row];
        if (BIASMODE == 2) v += bias[col];
        if (OUTF32)
          ((float*)Cout)[(size_t)row * N + col] = v;
        else
          ((unsigned short*)Cout)[(size_t)row * N + col] = f2bf(v);
      }
    }
}

// ---------------- shared staging helper (512-thread blocks) -----------------
__device__ __forceinline__ void stage_half(const unsigned short* __restrict__ src,
                                           int K, unsigned short* dst, int tid) {
#pragma unroll
  for (int j = 0; j < 2; j++) {
    const int li = tid + j * 512;
    const int r = li >> 3;
    const int c16 = (li & 7) ^ (r & 7);
    GLOAD16(src + (size_t)r * K + c16 * 8, (char*)dst + li * 16);
  }
}

// ---------------- 256x256 8-phase GEMM (T2+T3+T4+T5) -- Yqk only ------------
__global__ __launch_bounds__(512, 2) void k_gemm_yqk(const unsigned short* __restrict__ A,
                                                     const unsigned short* __restrict__ BT,
                                                     unsigned short* __restrict__ Cout) {
  __shared__ unsigned short As[2][256 * 64];
  __shared__ unsigned short Bs[2][256 * 64];
  const int tid = threadIdx.x;
  const int lane = tid & 63, w = tid >> 6;
  const int g = lane >> 4, cc = lane & 15;
  const int wm = (w >> 2) * 128, wn = (w & 3) * 64;
  const int swz = (cc & 7) << 4;
  const int N = 4096, K = 2048;
  int id = blockIdx.x;
  id = (id & 7) * 32 + (id >> 3);              // 256 wgs -> 32/XCD contiguous
  const int m0 = (id >> 4) * 256, n0 = (id & 15) * 256;
  f32x4 acc[8][4] = {};
  const int T = K >> 6;                        // 32 K-tiles

  stage_half(BT + (size_t)n0 * K, K, Bs[0], tid);
  stage_half(A + (size_t)m0 * K, K, As[0], tid);
  stage_half(BT + (size_t)(n0 + 128) * K, K, Bs[0] + 8192, tid);
  stage_half(A + (size_t)(m0 + 128) * K, K, As[0] + 8192, tid);
  stage_half(BT + (size_t)n0 * K + 64, K, Bs[1], tid);
  stage_half(A + (size_t)m0 * K + 64, K, As[1], tid);
  asm volatile("s_waitcnt vmcnt(4)" ::: "memory");
  __builtin_amdgcn_s_barrier();

  for (int t = 0; t < T; ++t) {
    const int c = t & 1;
    const char* Ac = (const char*)As[c];
    const char* Bc = (const char*)Bs[c];
    bf16x8 ar[4][2], br[4][2];
    // -------- phase 1
#pragma unroll
    for (int m = 0; m < 4; m++)
#pragma unroll
      for (int kk = 0; kk < 2; kk++)
        ar[m][kk] = *(const bf16x8*)(Ac + (wm + m * 16 + cc) * 128 +
                                     ((kk * 64 + g * 16) ^ swz));
#pragma unroll
    for (int n = 0; n < 2; n++)
#pragma unroll
      for (int kk = 0; kk < 2; kk++)
        br[n][kk] = *(const bf16x8*)(Bc + (wn + n * 16 + cc) * 128 +
                                     ((kk * 64 + g * 16) ^ swz));
    stage_half(BT + (size_t)(n0 + 128) * K + ((t + 1) & (T - 1)) * 64, K,
               Bs[c ^ 1] + 8192, tid);
    __builtin_amdgcn_s_barrier();
    __builtin_amdgcn_sched_barrier(0);
    __builtin_amdgcn_s_setprio(1);
#pragma unroll
    for (int kk = 0; kk < 2; kk++)
#pragma unroll
      for (int m = 0; m < 4; m++)
#pragma unroll
        for (int n = 0; n < 2; n++)
          acc[m][n] = __builtin_amdgcn_mfma_f32_16x16x32_bf16(ar[m][kk], br[n][kk],
                                                              acc[m][n], 0, 0, 0);
    __builtin_amdgcn_s_setprio(0);
    __builtin_amdgcn_s_barrier();
    __builtin_amdgcn_sched_barrier(0);
    // -------- phase 2
#pragma unroll
    for (int n = 2; n < 4; n++)
#pragma unroll
      for (int kk = 0; kk < 2; kk++)
        br[n][kk] = *(const bf16x8*)(Bc + (wn + n * 16 + cc) * 128 +
                                     ((kk * 64 + g * 16) ^ swz));
    stage_half(A + (size_t)(m0 + 128) * K + ((t + 1) & (T - 1)) * 64, K,
               As[c ^ 1] + 8192, tid);
    __builtin_amdgcn_s_barrier();
    __builtin_amdgcn_sched_barrier(0);
    __builtin_amdgcn_s_setprio(1);
#pragma unroll
    for (int kk = 0; kk < 2; kk++)
#pragma unroll
      for (int m = 0; m < 4; m++)
#pragma unroll
        for (int n = 2; n < 4; n++)
          acc[m][n] = __builtin_amdgcn_mfma_f32_16x16x32_bf16(ar[m][kk], br[n][kk],
                                                              acc[m][n], 0, 0, 0);
    __builtin_amdgcn_s_setprio(0);
    __builtin_amdgcn_s_barrier();
    __builtin_amdgcn_sched_barrier(0);
    // -------- phase 3
#pragma unroll
    for (int m = 0; m < 4; m++)
#pragma unroll
      for (int kk = 0; kk < 2; kk++)
        ar[m][kk] = *(const bf16x8*)(Ac + (wm + (m + 4) * 16 + cc) * 128 +
                                     ((kk * 64 + g * 16) ^ swz));
    stage_half(BT + (size_t)n0 * K + ((t + 2) & (T - 1)) * 64, K, Bs[c], tid);
    __builtin_amdgcn_s_barrier();
    __builtin_amdgcn_sched_barrier(0);
    __builtin_amdgcn_s_setprio(1);
#pragma unroll
    for (int kk = 0; kk < 2; kk++)
#pragma unroll
      for (int m = 0; m < 4; m++)
#pragma unroll
        for (int n = 0; n < 2; n++)
          acc[m + 4][n] = __builtin_amdgcn_mfma_f32_16x16x32_bf16(ar[m][kk], br[n][kk],
                                                                  acc[m + 4][n], 0, 0, 0);
    __builtin_amdgcn_s_setprio(0);
    __builtin_amdgcn_s_barrier();
    __builtin_amdgcn_sched_barrier(0);
    // -------- phase 4
    stage_half(A + (size_t)m0 * K + ((t + 2) & (T - 1)) * 64, K, As[c], tid);
    __builtin_amdgcn_s_setprio(1);
#pragma unroll
    for (int kk = 0; kk < 2; kk++)
#pragma unroll
      for (int m = 0; m < 4; m++)
#pragma unroll
        for (int n = 2; n < 4; n++)
          acc[m + 4][n] = __builtin_amdgcn_mfma_f32_16x16x32_bf16(ar[m][kk], br[n][kk],
                                                                  acc[m + 4][n], 0, 0, 0);
    __builtin_amdgcn_s_setprio(0);
    if (t < T - 2)
      asm volatile("s_waitcnt vmcnt(4)" ::: "memory");
    else
      asm volatile("s_waitcnt vmcnt(0)" ::: "memory");
    __builtin_amdgcn_sched_barrier(0);
    __builtin_amdgcn_s_barrier();
    __builtin_amdgcn_sched_barrier(0);
  }

#pragma unroll
  for (int mi = 0; mi < 8; mi++)
#pragma unroll
    for (int n = 0; n < 4; n++) {
      const int col = n0 + wn + n * 16 + cc;
#pragma unroll
      for (int j = 0; j < 4; j++) {
        const int row = m0 + wm + mi * 16 + g * 4 + j;
        Cout[(size_t)row * N + col] = f2bf(acc[mi][n][j]);
      }
    }
}

// ---------------- QK epilogue: bias + RMSNorm + RoPE -> Q,K [b,h,s,d] ------
__global__ __launch_bounds__(256) void k_qk_epi(const unsigned short* __restrict__ Yqk, // [4096][4096]
                                                const float* __restrict__ q_b,
                                                const float* __restrict__ k_b,
                                                const float* __restrict__ nqw,
                                                const float* __restrict__ nkw,
                                                const float* __restrict__ freqs, // [1024][64][2]
                                                const int* __restrict__ inner_t, // [2][2]
                                                unsigned short* __restrict__ Q,
                                                unsigned short* __restrict__ K) {
  const int row = blockIdx.x;          // b*2048 + s
  const int b = row >> 11, s = row & 2047;
  const int t = threadIdx.x;
  const unsigned short* yr = Yqk + (size_t)row * 4096;
  bf16x8 yq = *(const bf16x8*)(yr + t * 8);
  bf16x8 yk = *(const bf16x8*)(yr + 2048 + t * 8);
  float4 qb0 = *(const float4*)(q_b + t * 8), qb1 = *(const float4*)(q_b + t * 8 + 4);
  float4 kb0 = *(const float4*)(k_b + t * 8), kb1 = *(const float4*)(k_b + t * 8 + 4);
  float q[8], k[8];
  q[0] = bf2f((unsigned short)yq[0]) + qb0.x; q[1] = bf2f((unsigned short)yq[1]) + qb0.y;
  q[2] = bf2f((unsigned short)yq[2]) + qb0.z; q[3] = bf2f((unsigned short)yq[3]) + qb0.w;
  q[4] = bf2f((unsigned short)yq[4]) + qb1.x; q[5] = bf2f((unsigned short)yq[5]) + qb1.y;
  q[6] = bf2f((unsigned short)yq[6]) + qb1.z; q[7] = bf2f((unsigned short)yq[7]) + qb1.w;
  k[0] = bf2f((unsigned short)yk[0]) + kb0.x; k[1] = bf2f((unsigned short)yk[1]) + kb0.y;
  k[2] = bf2f((unsigned short)yk[2]) + kb0.z; k[3] = bf2f((unsigned short)yk[3]) + kb0.w;
  k[4] = bf2f((unsigned short)yk[4]) + kb1.x; k[5] = bf2f((unsigned short)yk[5]) + kb1.y;
  k[6] = bf2f((unsigned short)yk[6]) + kb1.z; k[7] = bf2f((unsigned short)yk[7]) + kb1.w;
  float ssq = 0.f, ssk = 0.f;
#pragma unroll
  for (int j = 0; j < 8; j++) { ssq += q[j] * q[j]; ssk += k[j] * k[j]; }
#pragma unroll
  for (int off = 32; off; off >>= 1) {
    ssq += __shfl_xor(ssq, off);
    ssk += __shfl_xor(ssk, off);
  }
  __shared__ float red[8];
  const int w = t >> 6;
  if ((t & 63) == 0) { red[w] = ssq; red[4 + w] = ssk; }
  __syncthreads();
  const float sq = red[0] + red[1] + red[2] + red[3];
  const float sk = red[4] + red[5] + red[6] + red[7];
  const float rq = __builtin_amdgcn_rsqf(sq * (1.0f / 2048.0f) + 1e-6f);
  const float rk = __builtin_amdgcn_rsqf(sk * (1.0f / 2048.0f) + 1e-6f);
  float4 nq0 = *(const float4*)(nqw + t * 8), nq1 = *(const float4*)(nqw + t * 8 + 4);
  float4 nk0 = *(const float4*)(nkw + t * 8), nk1 = *(const float4*)(nkw + t * 8 + 4);
  q[0] *= rq * nq0.x; q[1] *= rq * nq0.y; q[2] *= rq * nq0.z; q[3] *= rq * nq0.w;
  q[4] *= rq * nq1.x; q[5] *= rq * nq1.y; q[6] *= rq * nq1.z; q[7] *= rq * nq1.w;
  k[0] *= rk * nk0.x; k[1] *= rk * nk0.y; k[2] *= rk * nk0.z; k[3] *= rk * nk0.w;
  k[4] *= rk * nk1.x; k[5] *= rk * nk1.y; k[6] *= rk * nk1.z; k[7] *= rk * nk1.w;
  // RoPE: s -> (f,h,w) with HW grid 8x16x16, pairs are adjacent elems
  const int f = s >> 8, hh = (s >> 4) & 15, ww = s & 15;
  const int it0 = inner_t[b * 2], it1 = inner_t[b * 2 + 1];
  const int trow = ((f >= it0) + (f >= it0 + it1)) * 4 + f;  // SHIFT=4
#pragma unroll
  for (int jj = 0; jj < 4; jj++) {
    const int c = (t * 4 + jj) & 63;              // pair idx within head (C=64)
    const int fr = (c < 22) ? trow : ((c < 43) ? hh : ww);  // CT=22, CT+CH=43
    const float cr = freqs[((size_t)fr * 64 + c) * 2];
    const float ci = freqs[((size_t)fr * 64 + c) * 2 + 1];
    float a = q[2 * jj], bb = q[2 * jj + 1];
    q[2 * jj] = a * cr - bb * ci; q[2 * jj + 1] = a * ci + bb * cr;
    a = k[2 * jj]; bb = k[2 * jj + 1];
    k[2 * jj] = a * cr - bb * ci; k[2 * jj + 1] = a * ci + bb * cr;
  }
  // fold attn scale and log2(e) into Q (softmax done in exp2 domain)
  const float QSCALE = 0.08838834764831845f * 1.4426950408889634f;
  bf16x8 oq, ok;
#pragma unroll
  for (int j = 0; j < 8; j++) {
    oq[j] = (short)f2bf(q[j] * QSCALE);
    ok[j] = (short)f2bf(k[j]);
  }
  const int head = t >> 4, d0 = (t & 15) * 8;
  const size_t off = ((size_t)(b * 16 + head) * 2048 + s) * 128 + d0;
  *(bf16x8*)(Q + off) = oq;
  *(bf16x8*)(K + off) = ok;
}

// ---------------- flash attention (R12 + crit-path micro-opts) --------------
// v7: (1) rs-reduce shfls + lloc update moved AFTER PV (off the P->PV chain);
// (2) v_max3-fusable fmax tree; (3) last iteration skips the tail barrier.
__global__ __launch_bounds__(512, 4) void k_attn(const unsigned short* __restrict__ Q,
                                                 const unsigned short* __restrict__ K,
                                                 const unsigned short* __restrict__ V,
                                                 unsigned short* __restrict__ O) {
  __shared__ unsigned short Ks[2][64 * 128];   // [key][d], byte ^= (key&7)<<4
  __shared__ unsigned short Vs[2][128 * 64];   // [d][key], byte ^= (d&7)<<4
  __shared__ unsigned short Ps[8 * 16 * 64];   // per-wave P [q][key], byte ^= (q&7)<<4
  const int tid = threadIdx.x;
  const int lane = tid & 63, w = tid >> 6;
  const int g = lane >> 4, cc = lane & 15;
  const int orig = blockIdx.x;                 // 512 blocks flat
  const int lid = (orig & 7) * 64 + (orig >> 3);  // XCD gets 64 consecutive lids
  const int bh = lid >> 4;                     // 4 full heads per XCD
  const int q0 = (lid & 15) * 128;
  const int b = bh >> 4, h = bh & 15;

  const unsigned short* Qb = Q + ((size_t)bh * 2048 + q0 + w * 16 + cc) * 128;
  bf16x8 qf[4];
#pragma unroll
  for (int kk = 0; kk < 4; kk++) qf[kk] = *(const bf16x8*)(Qb + kk * 32 + g * 8);

  const char* kbase = (const char*)(K + (size_t)bh * 2048 * 128);
  const char* vbase = (const char*)V + ((size_t)h * 128 * 4096 + (size_t)b * 2048) * 2;

  f32x4 acc[8] = {};
  float mloc = -3.0e38f, lloc = 0.f;           // per-lane stats for q = w*16+cc
  char* Pb = (char*)Ps + w * 2048 + cc * 128;
  const int psw = (cc & 7) << 4;
  const int gbase = (lane & 48) | (((lane >> 4) & 3) << 2);  // lane g*16 + g*4
  const f32x4 vzero = {0.f, 0.f, 0.f, 0.f};

#define ATTN_STAGE(s0, bi)                                                     \
  {                                                                            \
    const char* kt0 = kbase + (size_t)(s0) * 256;                              \
    const char* vt0 = vbase + (size_t)(s0) * 2;                                \
    char* Kd = (char*)(Ks[bi]);                                                \
    char* Vd = (char*)(Vs[bi]);                                                \
    _Pragma("unroll") for (int i = 0; i < 2; i++) {                            \
      const int li = i * 512 + tid;                                            \
      const int kr = li >> 4;                                                  \
      const int kc = ((li & 15) * 16) ^ ((kr & 7) << 4);                       \
      GLOAD16(kt0 + kr * 256 + kc, Kd + li * 16);                              \
      const int vd = li >> 3;                                                  \
      const int vc = ((li & 7) * 16) ^ ((vd & 7) << 4);                        \
      GLOAD16(vt0 + (size_t)vd * 8192 + vc, Vd + li * 16);                     \
    }                                                                          \
  }

  ATTN_STAGE(0, 0);
  for (int t = 0; t < 32; ++t) {
    const int cur = t & 1;
    if (t < 31) {
      ATTN_STAGE((t + 1) * 64, cur ^ 1);
      asm volatile("s_waitcnt vmcnt(4)" ::: "memory");  // tile t landed; t+1 in flight
    } else {
      asm volatile("s_waitcnt vmcnt(0)" ::: "memory");
    }
    __builtin_amdgcn_sched_barrier(0);
    __builtin_amdgcn_s_barrier();

    // S^T = K Q^T : lane (g,cc) holds S[key = n4*16+g*4+r][q = w*16+cc]
    const char* kcur = (const char*)(Ks[cur]);
    const int sw = (cc & 7) << 4;
    f32x4 sf[4] = {vzero, vzero, vzero, vzero};
    __builtin_amdgcn_s_setprio(1);
#pragma unroll
    for (int kk = 0; kk < 4; kk++) {
      const int ko = (kk * 64 + g * 16) ^ sw;
      bf16x8 kf0 = *(const bf16x8*)(kcur + (cc)*256 + ko);
      bf16x8 kf1 = *(const bf16x8*)(kcur + (16 + cc) * 256 + ko);
      bf16x8 kf2 = *(const bf16x8*)(kcur + (32 + cc) * 256 + ko);
      bf16x8 kf3 = *(const bf16x8*)(kcur + (48 + cc) * 256 + ko);
      sf[0] = __builtin_amdgcn_mfma_f32_16x16x32_bf16(kf0, qf[kk], sf[0], 0, 0, 0);
      sf[1] = __builtin_amdgcn_mfma_f32_16x16x32_bf16(kf1, qf[kk], sf[1], 0, 0, 0);
      sf[2] = __builtin_amdgcn_mfma_f32_16x16x32_bf16(kf2, qf[kk], sf[2], 0, 0, 0);
      sf[3] = __builtin_amdgcn_mfma_f32_16x16x32_bf16(kf3, qf[kk], sf[3], 0, 0, 0);
    }
    __builtin_amdgcn_s_setprio(0);

    // lane-local online softmax; v_max3-fusable tree (5+3 vs 15 fmax)
    float m0 = fmaxf(fmaxf(sf[0][0], sf[0][1]), sf[0][2]);
    float m1 = fmaxf(fmaxf(sf[0][3], sf[1][0]), sf[1][1]);
    float m2 = fmaxf(fmaxf(sf[1][2], sf[1][3]), sf[2][0]);
    float m3 = fmaxf(fmaxf(sf[2][1], sf[2][2]), sf[2][3]);
    float m4 = fmaxf(fmaxf(sf[3][0], sf[3][1]), sf[3][2]);
    float tm = fmaxf(fmaxf(m0, m1), m2);
    tm = fmaxf(fmaxf(tm, m3), m4);
    tm = fmaxf(tm, sf[3][3]);
    tm = fmaxf(tm, __shfl_xor(tm, 16));
    tm = fmaxf(tm, __shfl_xor(tm, 32));
    if (__any(tm > mloc + 8.0f)) {             // defer-max (T13, THR=8 log2 units)
      const float mn = fmaxf(mloc, tm);
      const float sc = __builtin_amdgcn_exp2f(mloc - mn);
      mloc = mn;
      lloc *= sc;
      f32x4 scv;
#pragma unroll
      for (int r = 0; r < 4; r++) scv[r] = __shfl(sc, gbase + r);
#pragma unroll
      for (int d4 = 0; d4 < 8; d4++) acc[d4] *= scv;
    }
    float rs = 0.f;
#pragma unroll
    for (int n4 = 0; n4 < 4; n4++) {
      const float p0 = __builtin_amdgcn_exp2f(sf[n4][0] - mloc);
      const float p1 = __builtin_amdgcn_exp2f(sf[n4][1] - mloc);
      const float p2 = __builtin_amdgcn_exp2f(sf[n4][2] - mloc);
      const float p3 = __builtin_amdgcn_exp2f(sf[n4][3] - mloc);
      rs += (p0 + p1) + (p2 + p3);
      unsigned lo, hi;
      asm("v_cvt_pk_bf16_f32 %0, %1, %2" : "=v"(lo) : "v"(p0), "v"(p1));
      asm("v_cvt_pk_bf16_f32 %0, %1, %2" : "=v"(hi) : "v"(p2), "v"(p3));
      uint2 pv_; pv_.x = lo; pv_.y = hi;
      *(uint2*)(Pb + ((n4 * 32 + g * 8) ^ psw)) = pv_;   // P[q=cc][n4*16+g*4 ..+3]
    }

    // O += P V   (A = P[q][k] from Ps, B = V^T from Vs)
    const char* vcur = (const char*)(Vs[cur]);
    __builtin_amdgcn_s_setprio(1);
#pragma unroll
    for (int ks = 0; ks < 2; ks++) {
      bf16x8 pf = *(const bf16x8*)(Pb + ((ks * 64 + g * 16) ^ psw));
#pragma unroll
      for (int d4 = 0; d4 < 8; d4++) {
        const int dd = d4 * 16 + cc;
        bf16x8 vf = *(const bf16x8*)(vcur + dd * 128 +
                                     ((ks * 64 + g * 16) ^ ((dd & 7) << 4)));
        acc[d4] = __builtin_amdgcn_mfma_f32_16x16x32_bf16(pf, vf, acc[d4], 0, 0, 0);
      }
    }
    __builtin_amdgcn_s_setprio(0);

    // l-reduction off the critical path (needed only next iter / epilogue)
    rs += __shfl_xor(rs, 16);
    rs += __shfl_xor(rs, 32);
    lloc += rs;

    if (t < 31) {
      asm volatile("s_waitcnt lgkmcnt(0)" ::: "memory");  // reads done pre-overwrite
      __builtin_amdgcn_sched_barrier(0);
      __builtin_amdgcn_s_barrier();
    }
  }
#undef ATTN_STAGE

  const float invl = __builtin_amdgcn_rcpf(lloc);
  float ir[4];
#pragma unroll
  for (int r = 0; r < 4; r++) ir[r] = __shfl(invl, gbase + r);
  unsigned short* Ob = O + (size_t)(b * 2048 + q0 + w * 16) * 2048 + h * 128;
#pragma unroll
  for (int d4 = 0; d4 < 8; d4++)
#pragma unroll
    for (int r = 0; r < 4; r++)
      Ob[(size_t)(g * 4 + r) * 2048 + d4 * 16 + cc] = f2bf(acc[d4][r] * ir[r]);
}

// ---------------------------------------------------------------------------
extern "C" void kernel_launch(void* const* d_in, const int* in_sizes, int n_in,
                              void* d_out, int out_size, void* d_ws, size_t ws_size,
                              hipStream_t stream) {
  const float* x     = (const float*)d_in[0];
  const float* q_w   = (const float*)d_in[1];
  const float* q_b   = (const float*)d_in[2];
  const float* k_w   = (const float*)d_in[3];
  const float* k_b   = (const float*)d_in[4];
  const float* v_w   = (const float*)d_in[5];
  const float* v_b   = (const float*)d_in[6];
  const float* o_w   = (const float*)d_in[7];
  const float* o_b   = (const float*)d_in[8];
  const float* nqw   = (const float*)d_in[9];
  const float* nkw   = (const float*)d_in[10];
  const float* freqs = (const float*)d_in[11];
  const int* inner_t = (const int*)d_in[14];

  const size_t NEED = (size_t)112 << 20;
  if (ws_size < NEED) return;

  char* ws = (char*)d_ws;
  unsigned short* xb   = (unsigned short*)(ws);                      // 16MB (later Q)
  unsigned short* WqkT = (unsigned short*)(ws + ((size_t)16 << 20)); // 16MB (later O)
  unsigned short* WvT  = (unsigned short*)(ws + ((size_t)32 << 20)); // 8MB
  unsigned short* WoT  = (unsigned short*)(ws + ((size_t)40 << 20)); // 8MB
  unsigned short* Yqk  = (unsigned short*)(ws + ((size_t)48 << 20)); // 32MB
  unsigned short* Vt   = (unsigned short*)(ws + ((size_t)80 << 20)); // 16MB
  unsigned short* Kr   = (unsigned short*)(ws + ((size_t)96 << 20)); // 16MB
  unsigned short* Qr   = xb;     // reuse: xb dead after V GEMM
  unsigned short* Orow = WqkT;   // reuse: WqkT dead after Yqk GEMM

  // fused: x convert + 4 weight transposes (1 launch)
  k_prep<<<8192, 256, 0, stream>>>(x, xb, q_w, k_w, v_w, o_w, WqkT, WvT, WoT);
  // Yqk[b*S+s][0:2048]=x@q_w, [2048:4096]=x@k_w  (256 wgs, 8-phase 256^2)
  k_gemm_yqk<<<256, 512, 0, stream>>>(xb, WqkT, Yqk);
  // Vt[h*128+d][b*S+s] = (x@v_w)^T + v_b[row]  (BK=64 swizzled 128^2)
  k_gemm<0, 1><<<dim3(32, 16), 256, 0, stream>>>(WvT, xb, Vt, v_b, 2048, 4096, 2048);
  k_qk_epi<<<4096, 256, 0, stream>>>(Yqk, q_b, k_b, nqw, nkw, freqs, inner_t, Qr, Kr);
  k_attn<<<512, 512, 0, stream>>>(Qr, Kr, Vt, Orow);
  // out = O @ o_w + o_b  (f32, BK=64 swizzled 128^2)
  k_gemm<1, 2><<<dim3(16, 32), 256, 0, stream>>>(Orow, WoT, (float*)d_out, o_b, 4096, 2048, 2048);
}